// Round 1
// baseline (1042.043 us; speedup 1.0000x reference)
//
#include <hip/hip_runtime.h>

#define ULL unsigned long long

// problem constants
#define BB 4
#define NP 4096
#define GG 4096
#define HH 64
#define EPSF 1e-5f

// workspace float offsets (ws is float*)
#define WT_OFF      0u
#define WT_PER_CONV 110592u      // 27*64*64, layout [off][co][ci]
#define IDX_OFF     442368u      // B*G*8 ints
#define VOL0_OFF    573440u      // padded [4][18][18][18][64]
#define T1_OFF      2066432u     // [4][16][16][16][64]
#define A1_OFF      3115008u     // padded
#define T2_OFF      4608000u
#define VOL1_OFF    5656576u     // padded [4][10][10][10][64]
#define T3_OFF      5912576u     // [4][8][8][8][64]
#define A3_OFF      6043648u     // padded
#define T4_OFF      6299648u
#define STATS_OFF   6430720u     // sA[4][128], sF[128], sB[4][64]
#define TOTAL_F     6431616u
#define ZERO_N4     ((TOTAL_F - VOL0_OFF) / 4u)

__device__ __forceinline__ float gelu_tanh(float v) {
  // jax.nn.gelu(approximate=True): 0.5*x*(1+tanh(sqrt(2/pi)*(x+0.044715 x^3)))
  float inner = 0.7978845608028654f * (v + 0.044715f * v * v * v);
  return 0.5f * v * (1.0f + tanhf(inner));
}

__device__ __forceinline__ float lin16(int i) {
  // jnp.linspace(-1,1,16) element i (f32 iota*delta+start)
  return -1.0f + (float)i * (2.0f / 15.0f);
}

// ---------------------------------------------------------------- zero scratch
__global__ __launch_bounds__(256) void k_zero(float4* __restrict__ p, unsigned n4) {
  unsigned i = blockIdx.x * 256u + threadIdx.x;
  if (i < n4) p[i] = make_float4(0.f, 0.f, 0.f, 0.f);
}

// ------------------------------------------------- transpose conv weights
// conv_w [2][2][co=64][ci=64][3][3][3] -> wt [conv][off=27][co][ci]
__global__ __launch_bounds__(256) void k_prep_wt(const float* __restrict__ cw,
                                                 float* __restrict__ wt) {
  unsigned i = blockIdx.x * 256u + threadIdx.x;
  if (i >= 442368u) return;
  unsigned conv = i / WT_PER_CONV;
  unsigned r = i - conv * WT_PER_CONV;
  unsigned off = r >> 12;          // /4096
  unsigned q = r & 4095u;
  unsigned co = q >> 6, ci = q & 63u;
  wt[i] = cw[(conv * 4096u + co * 64u + ci) * 27u + off];
}

// ---------------------------------------------------------------- brute KNN
// one wave per voxel; pos[b] staged in LDS; per-lane sorted top-8 of
// (sortable_dist<<32)|idx keys; cross-lane 8-round min-reduce merge.
__global__ __launch_bounds__(256) void k_knn(const float* __restrict__ pos,
                                             int* __restrict__ idxo) {
  __shared__ float ps[NP * 3];
  int b = blockIdx.x >> 10;                      // 1024 blocks per batch
  const float* pb = pos + b * NP * 3;
  for (int t = threadIdx.x; t < NP * 3; t += 256) ps[t] = pb[t];
  __syncthreads();
  int lane = threadIdx.x & 63, wave = threadIdx.x >> 6;
  int g = ((blockIdx.x & 1023) << 2) | wave;
  float gx = lin16(g >> 8), gy = lin16((g >> 4) & 15), gz = lin16(g & 15);
  float gn = gx * gx + gy * gy + gz * gz;
  ULL kk[8];
#pragma unroll
  for (int i = 0; i < 8; ++i) kk[i] = ~0ULL;
  for (int t = 0; t < 64; ++t) {
    int p = (t << 6) | lane;
    float px = ps[3 * p], py = ps[3 * p + 1], pz = ps[3 * p + 2];
    float pn = px * px + py * py + pz * pz;
    float dt = gx * px + gy * py + gz * pz;
    float d = (gn + pn) - 2.0f * dt;             // mirror reference formula
    unsigned u = __float_as_uint(d);
    u ^= (unsigned)((int)u >> 31) | 0x80000000u; // sortable-uint mapping
    ULL key = ((ULL)u << 32) | (unsigned)p;      // tie -> lower index first
    if (key < kk[7]) {
      kk[7] = key;
#pragma unroll
      for (int s = 7; s >= 1; --s) {             // one insertion-sort pass
        ULL a = kk[s - 1], c = kk[s];
        bool sw = c < a;
        kk[s - 1] = sw ? c : a;
        kk[s] = sw ? a : c;
      }
    }
  }
  // merge 64 sorted lists: 8 rounds of wave-wide min
  ULL win = 0;
#pragma unroll
  for (int r = 0; r < 8; ++r) {
    ULL m = kk[0];
#pragma unroll
    for (int s = 1; s < 64; s <<= 1) {
      ULL o = __shfl_xor(m, s, 64);
      m = (o < m) ? o : m;
    }
    if (kk[0] == m) {                            // unique keys: one owner pops
#pragma unroll
      for (int q = 0; q < 7; ++q) kk[q] = kk[q + 1];
      kk[7] = ~0ULL;
    }
    if (lane == r) win = m;
  }
  if (lane < 8) idxo[(((b << 12) | g) << 3) + lane] = (int)(win & 0xFFFFFFFFULL);
}

// -------------------------------------------------- bipartite conv + update MLP
// wave per 4 voxels, lane = channel. 64x64 matvecs via readlane broadcast with
// register-resident weight columns (no LDS pipe pressure).
__global__ __launch_bounds__(256) void k_mlp(
    const float* __restrict__ pos, const float* __restrict__ xf,
    const float* __restrict__ w1, const float* __restrict__ b1,
    const float* __restrict__ w2, const float* __restrict__ b2,
    const float* __restrict__ fw, const float* __restrict__ fb,
    const float* __restrict__ uw, const float* __restrict__ ub,
    const int* __restrict__ idx, float* __restrict__ vol0) {
  int lane = threadIdx.x & 63, wave = threadIdx.x >> 6;
  float w2c[64], uwc[64];
#pragma unroll
  for (int j = 0; j < 64; ++j) w2c[j] = w2[j * 64 + lane];
#pragma unroll
  for (int j = 0; j < 64; ++j) uwc[j] = uw[j * 64 + lane];
  float w10 = w1[lane], w11 = w1[64 + lane], w12 = w1[128 + lane];
  float b1c = b1[lane], b2c = b2[lane];
  float fw0 = fw[lane], fw1 = fw[64 + lane], fw2 = fw[128 + lane], fbc = fb[lane];
  float ubc = ub[lane];
  int wg = blockIdx.x * 4 + wave;                // 4096 waves
  int b = wg >> 10;
  int g0 = (wg & 1023) * 4;
  for (int v = 0; v < 4; ++v) {
    int g = g0 + v;
    float gx = lin16(g >> 8), gy = lin16((g >> 4) & 15), gz = lin16(g & 15);
    float acc = 0.0f;
    for (int k = 0; k < 8; ++k) {
      int p = idx[(((b << 12) | g) << 3) + k];
      const float* pp = pos + (b * NP + p) * 3;
      float r0 = pp[0] - gx, r1 = pp[1] - gy, r2 = pp[2] - gz;
      float h1 = gelu_tanh(fmaf(r2, w12, fmaf(r1, w11, fmaf(r0, w10, b1c))));
      float pe = b2c;
#pragma unroll
      for (int j = 0; j < 64; ++j) {
        float hj = __uint_as_float(__builtin_amdgcn_readlane(__float_as_uint(h1), j));
        pe = fmaf(hj, w2c[j], pe);
      }
      const float* xp = xf + (b * NP + p) * 3;
      float fe = fmaf(xp[2], fw2, fmaf(xp[1], fw1, fmaf(xp[0], fw0, fbc)));
      acc = fmaf(pe, fe, acc);
    }
    acc *= 0.125f;                               // mean over K=8
    float hp = ubc;
#pragma unroll
    for (int j = 0; j < 64; ++j) {
      float aj = __uint_as_float(__builtin_amdgcn_readlane(__float_as_uint(acc), j));
      hp = fmaf(aj, uwc[j], hp);
    }
    float h = gelu_tanh(hp);
    // permute (0,4,3,2,1): voxel g=i*256+j*16+k -> (z,y,x)=(k,j,i); +1 halo
    int z = g & 15, y = (g >> 4) & 15, x = g >> 8;
    vol0[(((b * 18 + z + 1) * 18 + y + 1) * 18 + x + 1) * 64 + lane] = h;
  }
}

// ---------------------------------------------------------------- conv3d 3x3x3
// blockDim=64 (lane=co) so input addresses are blockIdx-uniform -> scalar loads.
// Input is zero-haloed channels-last; conv bias skipped (cancels in BN).
// Also accumulates per-channel sum/sumsq for BN via global fp32 atomics.
template <int Z, int VPW>
__global__ __launch_bounds__(64) void k_conv(const float* __restrict__ in,
                                             const float* __restrict__ wt,
                                             float* __restrict__ out,
                                             float* __restrict__ stats) {
  constexpr int P = Z + 2;
  int lane = threadIdx.x;
  int vox0 = blockIdx.x * VPW;                   // VPW consecutive-x voxels
  int b = vox0 / (Z * Z * Z);
  int r = vox0 - b * (Z * Z * Z);
  int z = r / (Z * Z);
  int r2 = r - z * (Z * Z);
  int y = r2 / Z;
  int x0 = r2 - y * Z;
  float acc[VPW];
#pragma unroll
  for (int v = 0; v < VPW; ++v) acc[v] = 0.0f;
  const float* wl = wt + lane * 64;              // wt[off][co=lane][ci]
  for (int dz = 0; dz < 3; ++dz)
    for (int dy = 0; dy < 3; ++dy) {
      const float* ip = in + (((b * P + z + dz) * P + y + dy) * P + x0) * 64;
#pragma unroll
      for (int dx = 0; dx < 3; ++dx) {
        const float* wo = wl + (dz * 9 + dy * 3 + dx) * 4096;
#pragma unroll
        for (int c8 = 0; c8 < 64; c8 += 8) {
          float4 wa = *(const float4*)(wo + c8);
          float4 wb = *(const float4*)(wo + c8 + 4);
#pragma unroll
          for (int v = 0; v < VPW; ++v) {
            const float* iv = ip + (v + dx) * 64 + c8;
            float4 ia = *(const float4*)(iv);
            float4 ib = *(const float4*)(iv + 4);
            acc[v] = fmaf(wa.x, ia.x, acc[v]);
            acc[v] = fmaf(wa.y, ia.y, acc[v]);
            acc[v] = fmaf(wa.z, ia.z, acc[v]);
            acc[v] = fmaf(wa.w, ia.w, acc[v]);
            acc[v] = fmaf(wb.x, ib.x, acc[v]);
            acc[v] = fmaf(wb.y, ib.y, acc[v]);
            acc[v] = fmaf(wb.z, ib.z, acc[v]);
            acc[v] = fmaf(wb.w, ib.w, acc[v]);
          }
        }
      }
    }
  float s = 0.0f, s2 = 0.0f;
#pragma unroll
  for (int v = 0; v < VPW; ++v) {
    out[(vox0 + v) * 64 + lane] = acc[v];
    s += acc[v];
    s2 = fmaf(acc[v], acc[v], s2);
  }
  atomicAdd(&stats[lane * 2], s);
  atomicAdd(&stats[lane * 2 + 1], s2);
}

// ------------------------------------------------------------ relu(bn(x)) -> padded
template <int Z>
__global__ __launch_bounds__(256) void k_bnrelu(const float* __restrict__ t,
                                                const float* __restrict__ stats,
                                                float* __restrict__ outp,
                                                float inv_cnt) {
  constexpr int P = Z + 2;
  unsigned i = blockIdx.x * 256u + threadIdx.x;
  int c = i & 63;
  int vox = i >> 6;
  int x = vox % Z;
  int q = vox / Z;
  int y = q % Z;
  q /= Z;
  int z = q % Z;
  int b = q / Z;
  float m = stats[c * 2] * inv_cnt;
  float var = stats[c * 2 + 1] * inv_cnt - m * m;
  float rs = 1.0f / sqrtf(var + EPSF);
  float v = (t[i] - m) * rs;
  outp[(((b * P + z + 1) * P + y + 1) * P + x + 1) * 64 + c] = v > 0.0f ? v : 0.0f;
}

// --------------------------------- vol = relu(vol0 + bn(t2)) then 2x2x2 maxpool
__global__ __launch_bounds__(256) void k_residpool(const float* __restrict__ vol0,
                                                   const float* __restrict__ t2,
                                                   const float* __restrict__ stats,
                                                   float* __restrict__ vol1) {
  unsigned i = blockIdx.x * 256u + threadIdx.x;  // < 131072
  int c = i & 63;
  int pv = i >> 6;
  int xp = pv & 7, yp = (pv >> 3) & 7, zp = (pv >> 6) & 7, b = pv >> 9;
  float m = stats[c * 2] * (1.0f / 16384.0f);
  float var = stats[c * 2 + 1] * (1.0f / 16384.0f) - m * m;
  float rs = 1.0f / sqrtf(var + EPSF);
  float best = 0.0f;                             // relu outputs are >= 0
  for (int dz = 0; dz < 2; ++dz)
    for (int dy = 0; dy < 2; ++dy)
      for (int dx = 0; dx < 2; ++dx) {
        int z = 2 * zp + dz, y = 2 * yp + dy, x = 2 * xp + dx;
        float a = vol0[(((b * 18 + z + 1) * 18 + y + 1) * 18 + x + 1) * 64 + c];
        float t = t2[(b * 4096 + z * 256 + y * 16 + x) * 64 + c];
        float u = a + (t - m) * rs;
        u = u > 0.0f ? u : 0.0f;
        best = u > best ? u : best;
      }
  vol1[(((b * 10 + zp + 1) * 10 + yp + 1) * 10 + xp + 1) * 64 + c] = best;
}

// -------------------- vol2 = relu(vol1 + bn(t4)); only its BN stats are needed
__global__ __launch_bounds__(256) void k_resid2(const float* __restrict__ vol1,
                                                const float* __restrict__ t4,
                                                const float* __restrict__ stats,
                                                float* __restrict__ sF,
                                                float* __restrict__ sB) {
  __shared__ float ls[64], ls2[64];
  if (threadIdx.x < 64) { ls[threadIdx.x] = 0.0f; ls2[threadIdx.x] = 0.0f; }
  __syncthreads();
  unsigned i = blockIdx.x * 256u + threadIdx.x;  // < 131072
  int c = i & 63;
  int pv = i >> 6;
  int x = pv & 7, y = (pv >> 3) & 7, z = (pv >> 6) & 7, b = pv >> 9;
  float m = stats[c * 2] * (1.0f / 2048.0f);
  float var = stats[c * 2 + 1] * (1.0f / 2048.0f) - m * m;
  float rs = 1.0f / sqrtf(var + EPSF);
  float a = vol1[(((b * 10 + z + 1) * 10 + y + 1) * 10 + x + 1) * 64 + c];
  float u = a + (t4[i] - m) * rs;
  u = u > 0.0f ? u : 0.0f;
  atomicAdd(&ls[c], u);
  atomicAdd(&ls2[c], u * u);
  __syncthreads();
  if (threadIdx.x < 64) {                        // block spans a single batch
    int cc = threadIdx.x;
    atomicAdd(&sF[cc * 2], ls[cc]);
    atomicAdd(&sF[cc * 2 + 1], ls2[cc]);
    atomicAdd(&sB[b * 64 + cc], ls[cc]);
  }
}

// ------------- final bn affine + spatial mean pool + linear head -> [4,16]
__global__ __launch_bounds__(64) void k_final(const float* __restrict__ sF,
                                              const float* __restrict__ sB,
                                              const float* __restrict__ ong,
                                              const float* __restrict__ onb,
                                              const float* __restrict__ row,
                                              const float* __restrict__ rob,
                                              float* __restrict__ outp) {
  __shared__ float pl[4][64];
  int c = threadIdx.x;
  float m = sF[c * 2] * (1.0f / 2048.0f);
  float var = sF[c * 2 + 1] * (1.0f / 2048.0f) - m * m;
  float rs = 1.0f / sqrtf(var + EPSF);
  float gg = ong[c], bb = onb[c];
  for (int b = 0; b < 4; ++b)
    pl[b][c] = (sB[b * 64 + c] * (1.0f / 512.0f) - m) * rs * gg + bb;
  __syncthreads();
  int b = threadIdx.x >> 4, o = threadIdx.x & 15;
  float s = rob[o];
  for (int j = 0; j < 64; ++j) s = fmaf(pl[b][j], row[j * 16 + o], s);
  outp[b * 16 + o] = s;
}

extern "C" void kernel_launch(void* const* d_in, const int* in_sizes, int n_in,
                              void* d_out, int out_size, void* d_ws, size_t ws_size,
                              hipStream_t stream) {
  (void)in_sizes; (void)n_in; (void)out_size; (void)ws_size;
  const float* pos = (const float*)d_in[0];
  const float* xf  = (const float*)d_in[1];
  const float* pw1 = (const float*)d_in[2];
  const float* pb1 = (const float*)d_in[3];
  const float* pw2 = (const float*)d_in[4];
  const float* pb2 = (const float*)d_in[5];
  const float* fw  = (const float*)d_in[6];
  const float* fb  = (const float*)d_in[7];
  const float* uw  = (const float*)d_in[8];
  const float* ubp = (const float*)d_in[9];
  const float* cw  = (const float*)d_in[10];
  // d_in[11] = conv_b: unused (training-mode BN cancels conv bias exactly)
  const float* ong = (const float*)d_in[12];
  const float* onb = (const float*)d_in[13];
  const float* row = (const float*)d_in[14];
  const float* rob = (const float*)d_in[15];

  float* ws   = (float*)d_ws;
  float* wt   = ws + WT_OFF;
  int*   idx  = (int*)(ws + IDX_OFF);
  float* vol0 = ws + VOL0_OFF;
  float* t1   = ws + T1_OFF;
  float* a1   = ws + A1_OFF;
  float* t2   = ws + T2_OFF;
  float* vol1 = ws + VOL1_OFF;
  float* t3   = ws + T3_OFF;
  float* a3   = ws + A3_OFF;
  float* t4   = ws + T4_OFF;
  float* sA   = ws + STATS_OFF;   // 4 convs x [64][2]
  float* sF   = sA + 512;
  float* sB   = sF + 128;

  // zero padded volumes (halo!) + all stat accumulators (ws is poisoned 0xAA)
  k_zero<<<(ZERO_N4 + 255) / 256, 256, 0, stream>>>((float4*)(ws + VOL0_OFF), ZERO_N4);
  k_prep_wt<<<1728, 256, 0, stream>>>(cw, wt);
  k_knn<<<4096, 256, 0, stream>>>(pos, idx);
  k_mlp<<<1024, 256, 0, stream>>>(pos, xf, pw1, pb1, pw2, pb2, fw, fb, uw, ubp, idx, vol0);
  // block 0 (16^3)
  k_conv<16, 8><<<2048, 64, 0, stream>>>(vol0, wt, t1, sA);
  k_bnrelu<16><<<4096, 256, 0, stream>>>(t1, sA, a1, 1.0f / 16384.0f);
  k_conv<16, 8><<<2048, 64, 0, stream>>>(a1, wt + WT_PER_CONV, t2, sA + 128);
  k_residpool<<<512, 256, 0, stream>>>(vol0, t2, sA + 128, vol1);
  // block 1 (8^3)
  k_conv<8, 2><<<1024, 64, 0, stream>>>(vol1, wt + 2 * WT_PER_CONV, t3, sA + 256);
  k_bnrelu<8><<<512, 256, 0, stream>>>(t3, sA + 256, a3, 1.0f / 2048.0f);
  k_conv<8, 2><<<1024, 64, 0, stream>>>(a3, wt + 3 * WT_PER_CONV, t4, sA + 384);
  k_resid2<<<512, 256, 0, stream>>>(vol1, t4, sA + 384, sF, sB);
  // head
  k_final<<<1, 64, 0, stream>>>(sF, sB, ong, onb, row, rob, (float*)d_out);
}

// Round 2
// 708.874 us; speedup vs baseline: 1.4700x; 1.4700x over previous
//
#include <hip/hip_runtime.h>

#define ULL unsigned long long

// problem constants
#define BB 4
#define NP 4096
#define GG 4096
#define HH 64
#define EPSF 1e-5f

// workspace float offsets (ws is float*)
#define WT_OFF      0u
#define WT_PER_CONV 110592u      // 27*64*64, layout [off][co][ci]
#define IDX_OFF     442368u      // B*G*8 ints
#define VOL0_OFF    573440u      // padded [4][18][18][18][64]
#define A1_OFF      2066432u     // padded [4][18][18][18][64]
#define VOL1_OFF    3559424u     // padded [4][10][10][10][64]
#define A3_OFF      3815424u     // padded [4][10][10][10][64]
#define STATS_OFF   4071424u     // sA[4][128], sF[128], sB[4][64]
#define T1_OFF      4072320u     // [4][16][16][16][64]
#define T2_OFF      5120896u
#define T3_OFF      6169472u     // [4][8][8][8][64]
#define T4_OFF      6300544u
#define TOTAL_F     6431616u
#define ZERO_N4     ((T1_OFF - VOL0_OFF) / 4u)   // zero padded vols + stats only

__device__ __forceinline__ float gelu_tanh(float v) {
  // jax.nn.gelu(approximate=True): 0.5*x*(1+tanh(sqrt(2/pi)*(x+0.044715 x^3)))
  float inner = 0.7978845608028654f * (v + 0.044715f * v * v * v);
  return 0.5f * v * (1.0f + tanhf(inner));
}

__device__ __forceinline__ float lin16(int i) {
  // jnp.linspace(-1,1,16) element i (f32 iota*delta+start)
  return -1.0f + (float)i * (2.0f / 15.0f);
}

// ---------------------------------------------------------------- zero scratch
__global__ __launch_bounds__(256) void k_zero(float4* __restrict__ p, unsigned n4) {
  unsigned i = blockIdx.x * 256u + threadIdx.x;
  if (i < n4) p[i] = make_float4(0.f, 0.f, 0.f, 0.f);
}

// ------------------------------------------------- transpose conv weights
// conv_w [2][2][co=64][ci=64][3][3][3] -> wt [conv][off=27][co][ci]
__global__ __launch_bounds__(256) void k_prep_wt(const float* __restrict__ cw,
                                                 float* __restrict__ wt) {
  unsigned i = blockIdx.x * 256u + threadIdx.x;
  if (i >= 442368u) return;
  unsigned conv = i / WT_PER_CONV;
  unsigned r = i - conv * WT_PER_CONV;
  unsigned off = r >> 12;          // /4096
  unsigned q = r & 4095u;
  unsigned co = q >> 6, ci = q & 63u;
  wt[i] = cw[(conv * 4096u + co * 64u + ci) * 27u + off];
}

// ---------------------------------------------------------------- brute KNN
// one wave per voxel; pos[b] staged in LDS; per-lane sorted top-8 of
// (sortable_dist<<32)|idx keys; cross-lane 8-round min-reduce merge.
__global__ __launch_bounds__(256) void k_knn(const float* __restrict__ pos,
                                             int* __restrict__ idxo) {
  __shared__ float ps[NP * 3];
  int b = blockIdx.x >> 10;                      // 1024 blocks per batch
  const float* pb = pos + b * NP * 3;
  for (int t = threadIdx.x; t < NP * 3; t += 256) ps[t] = pb[t];
  __syncthreads();
  int lane = threadIdx.x & 63, wave = threadIdx.x >> 6;
  int g = ((blockIdx.x & 1023) << 2) | wave;
  float gx = lin16(g >> 8), gy = lin16((g >> 4) & 15), gz = lin16(g & 15);
  float gn = gx * gx + gy * gy + gz * gz;
  ULL kk[8];
#pragma unroll
  for (int i = 0; i < 8; ++i) kk[i] = ~0ULL;
  for (int t = 0; t < 64; ++t) {
    int p = (t << 6) | lane;
    float px = ps[3 * p], py = ps[3 * p + 1], pz = ps[3 * p + 2];
    float pn = px * px + py * py + pz * pz;
    float dt = gx * px + gy * py + gz * pz;
    float d = (gn + pn) - 2.0f * dt;             // mirror reference formula
    unsigned u = __float_as_uint(d);
    u ^= (unsigned)((int)u >> 31) | 0x80000000u; // sortable-uint mapping
    ULL key = ((ULL)u << 32) | (unsigned)p;      // tie -> lower index first
    if (key < kk[7]) {
      kk[7] = key;
#pragma unroll
      for (int s = 7; s >= 1; --s) {             // one insertion-sort pass
        ULL a = kk[s - 1], c = kk[s];
        bool sw = c < a;
        kk[s - 1] = sw ? c : a;
        kk[s] = sw ? a : c;
      }
    }
  }
  // merge 64 sorted lists: 8 rounds of wave-wide min
  ULL win = 0;
#pragma unroll
  for (int r = 0; r < 8; ++r) {
    ULL m = kk[0];
#pragma unroll
    for (int s = 1; s < 64; s <<= 1) {
      ULL o = __shfl_xor(m, s, 64);
      m = (o < m) ? o : m;
    }
    if (kk[0] == m) {                            // unique keys: one owner pops
#pragma unroll
      for (int q = 0; q < 7; ++q) kk[q] = kk[q + 1];
      kk[7] = ~0ULL;
    }
    if (lane == r) win = m;
  }
  if (lane < 8) idxo[(((b << 12) | g) << 3) + lane] = (int)(win & 0xFFFFFFFFULL);
}

// -------------------------------------------------- bipartite conv + update MLP
// wave per 4 voxels, lane = channel. 64x64 matvecs via readlane broadcast with
// register-resident weight columns (no LDS pipe pressure).
__global__ __launch_bounds__(256) void k_mlp(
    const float* __restrict__ pos, const float* __restrict__ xf,
    const float* __restrict__ w1, const float* __restrict__ b1,
    const float* __restrict__ w2, const float* __restrict__ b2,
    const float* __restrict__ fw, const float* __restrict__ fb,
    const float* __restrict__ uw, const float* __restrict__ ub,
    const int* __restrict__ idx, float* __restrict__ vol0) {
  int lane = threadIdx.x & 63, wave = threadIdx.x >> 6;
  float w2c[64], uwc[64];
#pragma unroll
  for (int j = 0; j < 64; ++j) w2c[j] = w2[j * 64 + lane];
#pragma unroll
  for (int j = 0; j < 64; ++j) uwc[j] = uw[j * 64 + lane];
  float w10 = w1[lane], w11 = w1[64 + lane], w12 = w1[128 + lane];
  float b1c = b1[lane], b2c = b2[lane];
  float fw0 = fw[lane], fw1 = fw[64 + lane], fw2 = fw[128 + lane], fbc = fb[lane];
  float ubc = ub[lane];
  int wg = blockIdx.x * 4 + wave;                // 4096 waves
  int b = wg >> 10;
  int g0 = (wg & 1023) * 4;
  for (int v = 0; v < 4; ++v) {
    int g = g0 + v;
    float gx = lin16(g >> 8), gy = lin16((g >> 4) & 15), gz = lin16(g & 15);
    float acc = 0.0f;
    for (int k = 0; k < 8; ++k) {
      int p = idx[(((b << 12) | g) << 3) + k];
      const float* pp = pos + (b * NP + p) * 3;
      float r0 = pp[0] - gx, r1 = pp[1] - gy, r2 = pp[2] - gz;
      float h1 = gelu_tanh(fmaf(r2, w12, fmaf(r1, w11, fmaf(r0, w10, b1c))));
      float pe = b2c;
#pragma unroll
      for (int j = 0; j < 64; ++j) {
        float hj = __uint_as_float(__builtin_amdgcn_readlane(__float_as_uint(h1), j));
        pe = fmaf(hj, w2c[j], pe);
      }
      const float* xp = xf + (b * NP + p) * 3;
      float fe = fmaf(xp[2], fw2, fmaf(xp[1], fw1, fmaf(xp[0], fw0, fbc)));
      acc = fmaf(pe, fe, acc);
    }
    acc *= 0.125f;                               // mean over K=8
    float hp = ubc;
#pragma unroll
    for (int j = 0; j < 64; ++j) {
      float aj = __uint_as_float(__builtin_amdgcn_readlane(__float_as_uint(acc), j));
      hp = fmaf(aj, uwc[j], hp);
    }
    float h = gelu_tanh(hp);
    // permute (0,4,3,2,1): voxel g=i*256+j*16+k -> (z,y,x)=(k,j,i); +1 halo
    int z = g & 15, y = (g >> 4) & 15, x = g >> 8;
    vol0[(((b * 18 + z + 1) * 18 + y + 1) * 18 + x + 1) * 64 + lane] = h;
  }
}

// ---------------------------------------------------------------- conv3d 3x3x3
// ci-split conv: block = 4 waves, one x-row of Z voxels per block.
// Wave wv accumulates ci-chunks {q*4+wv}*4ci over q=0..3 (27 float4 weights in
// VGPRs per chunk, reloaded per q). Input row loads are wave-uniform (scalar).
// LDS-reduce the 4 waves -> final out + per-channel BN sum/sumsq atomics.
template <int Z>
__global__ __launch_bounds__(256) void k_conv2(const float* __restrict__ in,
                                               const float* __restrict__ wt,
                                               float* __restrict__ out,
                                               float* __restrict__ stats) {
  constexpr int P = Z + 2;
  __shared__ float red[4][Z * 64];
  __shared__ float ls[64], ls2[64];
  int lane = threadIdx.x & 63, wv = threadIdx.x >> 6;
  int row = blockIdx.x;                          // b*Z*Z + z*Z + y
  int b = row / (Z * Z);
  int r = row - b * (Z * Z);
  int z = r / Z;
  int y = r - z * Z;
  float acc[Z];
#pragma unroll
  for (int x = 0; x < Z; ++x) acc[x] = 0.0f;
  for (int q = 0; q < 4; ++q) {
    int ci0 = (q * 4 + wv) * 4;                  // this wave's ci chunk base
    float4 w[27];
#pragma unroll
    for (int o = 0; o < 27; ++o)
      w[o] = *(const float4*)(wt + (o * 64 + lane) * 64 + ci0);
#pragma unroll
    for (int dz = 0; dz < 3; ++dz)
#pragma unroll
      for (int dy = 0; dy < 3; ++dy) {
        const float* ip = in + (((b * P + z + dz) * P + y + dy) * P) * 64 + ci0;
        float4 i0 = *(const float4*)(ip);
        float4 i1 = *(const float4*)(ip + 64);
#pragma unroll
        for (int x = 0; x < Z; ++x) {
          float4 i2 = *(const float4*)(ip + (x + 2) * 64);
          const float4 w0 = w[(dz * 3 + dy) * 3 + 0];
          const float4 w1 = w[(dz * 3 + dy) * 3 + 1];
          const float4 w2 = w[(dz * 3 + dy) * 3 + 2];
          acc[x] = fmaf(w0.x, i0.x, acc[x]);
          acc[x] = fmaf(w0.y, i0.y, acc[x]);
          acc[x] = fmaf(w0.z, i0.z, acc[x]);
          acc[x] = fmaf(w0.w, i0.w, acc[x]);
          acc[x] = fmaf(w1.x, i1.x, acc[x]);
          acc[x] = fmaf(w1.y, i1.y, acc[x]);
          acc[x] = fmaf(w1.z, i1.z, acc[x]);
          acc[x] = fmaf(w1.w, i1.w, acc[x]);
          acc[x] = fmaf(w2.x, i2.x, acc[x]);
          acc[x] = fmaf(w2.y, i2.y, acc[x]);
          acc[x] = fmaf(w2.z, i2.z, acc[x]);
          acc[x] = fmaf(w2.w, i2.w, acc[x]);
          i0 = i1;
          i1 = i2;
        }
      }
  }
  if (threadIdx.x < 64) { ls[threadIdx.x] = 0.0f; ls2[threadIdx.x] = 0.0f; }
#pragma unroll
  for (int x = 0; x < Z; ++x) red[wv][x * 64 + lane] = acc[x];
  __syncthreads();
  float s = 0.0f, s2 = 0.0f;
  for (int i = threadIdx.x; i < Z * 64; i += 256) {
    float v = red[0][i] + red[1][i] + red[2][i] + red[3][i];
    out[row * (Z * 64) + i] = v;                 // i = x*64+co, contiguous
    s += v;
    s2 = fmaf(v, v, s2);
  }
  atomicAdd(&ls[lane], s);                       // co == threadIdx.x&63 for all i
  atomicAdd(&ls2[lane], s2);
  __syncthreads();
  if (threadIdx.x < 64) {
    atomicAdd(&stats[threadIdx.x * 2], ls[threadIdx.x]);
    atomicAdd(&stats[threadIdx.x * 2 + 1], ls2[threadIdx.x]);
  }
}

// ------------------------------------------------------------ relu(bn(x)) -> padded
template <int Z>
__global__ __launch_bounds__(256) void k_bnrelu(const float* __restrict__ t,
                                                const float* __restrict__ stats,
                                                float* __restrict__ outp,
                                                float inv_cnt) {
  constexpr int P = Z + 2;
  unsigned i = blockIdx.x * 256u + threadIdx.x;
  int c = i & 63;
  int vox = i >> 6;
  int x = vox % Z;
  int q = vox / Z;
  int y = q % Z;
  q /= Z;
  int z = q % Z;
  int b = q / Z;
  float m = stats[c * 2] * inv_cnt;
  float var = stats[c * 2 + 1] * inv_cnt - m * m;
  float rs = 1.0f / sqrtf(var + EPSF);
  float v = (t[i] - m) * rs;
  outp[(((b * P + z + 1) * P + y + 1) * P + x + 1) * 64 + c] = v > 0.0f ? v : 0.0f;
}

// --------------------------------- vol = relu(vol0 + bn(t2)) then 2x2x2 maxpool
__global__ __launch_bounds__(256) void k_residpool(const float* __restrict__ vol0,
                                                   const float* __restrict__ t2,
                                                   const float* __restrict__ stats,
                                                   float* __restrict__ vol1) {
  unsigned i = blockIdx.x * 256u + threadIdx.x;  // < 131072
  int c = i & 63;
  int pv = i >> 6;
  int xp = pv & 7, yp = (pv >> 3) & 7, zp = (pv >> 6) & 7, b = pv >> 9;
  float m = stats[c * 2] * (1.0f / 16384.0f);
  float var = stats[c * 2 + 1] * (1.0f / 16384.0f) - m * m;
  float rs = 1.0f / sqrtf(var + EPSF);
  float best = 0.0f;                             // relu outputs are >= 0
  for (int dz = 0; dz < 2; ++dz)
    for (int dy = 0; dy < 2; ++dy)
      for (int dx = 0; dx < 2; ++dx) {
        int z = 2 * zp + dz, y = 2 * yp + dy, x = 2 * xp + dx;
        float a = vol0[(((b * 18 + z + 1) * 18 + y + 1) * 18 + x + 1) * 64 + c];
        float t = t2[(b * 4096 + z * 256 + y * 16 + x) * 64 + c];
        float u = a + (t - m) * rs;
        u = u > 0.0f ? u : 0.0f;
        best = u > best ? u : best;
      }
  vol1[(((b * 10 + zp + 1) * 10 + yp + 1) * 10 + xp + 1) * 64 + c] = best;
}

// -------------------- vol2 = relu(vol1 + bn(t4)); only its BN stats are needed
__global__ __launch_bounds__(256) void k_resid2(const float* __restrict__ vol1,
                                                const float* __restrict__ t4,
                                                const float* __restrict__ stats,
                                                float* __restrict__ sF,
                                                float* __restrict__ sB) {
  __shared__ float ls[64], ls2[64];
  if (threadIdx.x < 64) { ls[threadIdx.x] = 0.0f; ls2[threadIdx.x] = 0.0f; }
  __syncthreads();
  unsigned i = blockIdx.x * 256u + threadIdx.x;  // < 131072
  int c = i & 63;
  int pv = i >> 6;
  int x = pv & 7, y = (pv >> 3) & 7, z = (pv >> 6) & 7, b = pv >> 9;
  float m = stats[c * 2] * (1.0f / 2048.0f);
  float var = stats[c * 2 + 1] * (1.0f / 2048.0f) - m * m;
  float rs = 1.0f / sqrtf(var + EPSF);
  float a = vol1[(((b * 10 + z + 1) * 10 + y + 1) * 10 + x + 1) * 64 + c];
  float u = a + (t4[i] - m) * rs;
  u = u > 0.0f ? u : 0.0f;
  atomicAdd(&ls[c], u);
  atomicAdd(&ls2[c], u * u);
  __syncthreads();
  if (threadIdx.x < 64) {                        // block spans a single batch
    int cc = threadIdx.x;
    atomicAdd(&sF[cc * 2], ls[cc]);
    atomicAdd(&sF[cc * 2 + 1], ls2[cc]);
    atomicAdd(&sB[b * 64 + cc], ls[cc]);
  }
}

// ------------- final bn affine + spatial mean pool + linear head -> [4,16]
__global__ __launch_bounds__(64) void k_final(const float* __restrict__ sF,
                                              const float* __restrict__ sB,
                                              const float* __restrict__ ong,
                                              const float* __restrict__ onb,
                                              const float* __restrict__ row,
                                              const float* __restrict__ rob,
                                              float* __restrict__ outp) {
  __shared__ float pl[4][64];
  int c = threadIdx.x;
  float m = sF[c * 2] * (1.0f / 2048.0f);
  float var = sF[c * 2 + 1] * (1.0f / 2048.0f) - m * m;
  float rs = 1.0f / sqrtf(var + EPSF);
  float gg = ong[c], bb = onb[c];
  for (int b = 0; b < 4; ++b)
    pl[b][c] = (sB[b * 64 + c] * (1.0f / 512.0f) - m) * rs * gg + bb;
  __syncthreads();
  int b = threadIdx.x >> 4, o = threadIdx.x & 15;
  float s = rob[o];
  for (int j = 0; j < 64; ++j) s = fmaf(pl[b][j], row[j * 16 + o], s);
  outp[b * 16 + o] = s;
}

extern "C" void kernel_launch(void* const* d_in, const int* in_sizes, int n_in,
                              void* d_out, int out_size, void* d_ws, size_t ws_size,
                              hipStream_t stream) {
  (void)in_sizes; (void)n_in; (void)out_size; (void)ws_size;
  const float* pos = (const float*)d_in[0];
  const float* xf  = (const float*)d_in[1];
  const float* pw1 = (const float*)d_in[2];
  const float* pb1 = (const float*)d_in[3];
  const float* pw2 = (const float*)d_in[4];
  const float* pb2 = (const float*)d_in[5];
  const float* fw  = (const float*)d_in[6];
  const float* fb  = (const float*)d_in[7];
  const float* uw  = (const float*)d_in[8];
  const float* ubp = (const float*)d_in[9];
  const float* cw  = (const float*)d_in[10];
  // d_in[11] = conv_b: unused (training-mode BN cancels conv bias exactly)
  const float* ong = (const float*)d_in[12];
  const float* onb = (const float*)d_in[13];
  const float* row = (const float*)d_in[14];
  const float* rob = (const float*)d_in[15];

  float* ws   = (float*)d_ws;
  float* wt   = ws + WT_OFF;
  int*   idx  = (int*)(ws + IDX_OFF);
  float* vol0 = ws + VOL0_OFF;
  float* a1   = ws + A1_OFF;
  float* vol1 = ws + VOL1_OFF;
  float* a3   = ws + A3_OFF;
  float* sA   = ws + STATS_OFF;   // 4 convs x [64][2]
  float* sF   = sA + 512;
  float* sB   = sF + 128;
  float* t1   = ws + T1_OFF;
  float* t2   = ws + T2_OFF;
  float* t3   = ws + T3_OFF;
  float* t4   = ws + T4_OFF;

  // zero padded volumes (halo!) + stat accumulators (ws is poisoned 0xAA)
  k_zero<<<(ZERO_N4 + 255) / 256, 256, 0, stream>>>((float4*)(ws + VOL0_OFF), ZERO_N4);
  k_prep_wt<<<1728, 256, 0, stream>>>(cw, wt);
  k_knn<<<4096, 256, 0, stream>>>(pos, idx);
  k_mlp<<<1024, 256, 0, stream>>>(pos, xf, pw1, pb1, pw2, pb2, fw, fb, uw, ubp, idx, vol0);
  // block 0 (16^3)
  k_conv2<16><<<1024, 256, 0, stream>>>(vol0, wt, t1, sA);
  k_bnrelu<16><<<4096, 256, 0, stream>>>(t1, sA, a1, 1.0f / 16384.0f);
  k_conv2<16><<<1024, 256, 0, stream>>>(a1, wt + WT_PER_CONV, t2, sA + 128);
  k_residpool<<<512, 256, 0, stream>>>(vol0, t2, sA + 128, vol1);
  // block 1 (8^3)
  k_conv2<8><<<256, 256, 0, stream>>>(vol1, wt + 2 * WT_PER_CONV, t3, sA + 256);
  k_bnrelu<8><<<512, 256, 0, stream>>>(t3, sA + 256, a3, 1.0f / 2048.0f);
  k_conv2<8><<<256, 256, 0, stream>>>(a3, wt + 3 * WT_PER_CONV, t4, sA + 384);
  k_resid2<<<512, 256, 0, stream>>>(vol1, t4, sA + 384, sF, sB);
  // head
  k_final<<<1, 64, 0, stream>>>(sF, sB, ong, onb, row, rob, (float*)d_out);
}

// Round 3
// 441.275 us; speedup vs baseline: 2.3614x; 1.6064x over previous
//
#include <hip/hip_runtime.h>

#define ULL unsigned long long
typedef unsigned short ush;
typedef __attribute__((ext_vector_type(8))) short s8v;   // 8 bf16 (4 VGPRs)
typedef __attribute__((ext_vector_type(4))) float f4v;   // MFMA accumulator

// problem constants
#define BB 4
#define NP 4096
#define HH 64
#define EPSF 1e-5f

// workspace float offsets (ws is float*)
#define WH_OFF      0u           // [4][27][64][64] bf16 hi = 442368 bf16 = 221184 f
#define WL_OFF      221184u      // lo part
#define WT_PER_CONV 110592u      // bf16 elements per conv
#define IDX_OFF     442368u      // B*G*8 ints = 131072
#define VOL0_OFF    573440u      // fp32 padded [4][18][18][18][64] = 1492992 f
#define V0H_OFF     2066432u     // bf16 padded hi = 746496 f   } reused as a1 hi
#define V0L_OFF     2812928u     // bf16 padded lo = 746496 f   } reused as a1 lo
#define T1_OFF      3559424u     // fp32 [4][16][16][16][64] = 1048576 f (reused as t2)
#define VOL1_OFF    4608000u     // fp32 padded [4][10][10][10][64] = 256000 f
#define V1H_OFF     4864000u     // 128000 f  } reused as a3 hi
#define V1L_OFF     4992000u     // 128000 f  } reused as a3 lo
#define T3_OFF      5120000u     // fp32 [4][8][8][8][64] = 131072 f (reused as t4)
#define STATS_OFF   5251072u     // sA[4][128], sF[128], sB[4][64] = 896 f

__device__ __forceinline__ ush f2bf(float f) {            // fp32 -> bf16 RNE
  unsigned u = __float_as_uint(f);
  return (ush)((u + 0x7FFFu + ((u >> 16) & 1u)) >> 16);
}
__device__ __forceinline__ float bf2f(ush h) { return __uint_as_float(((unsigned)h) << 16); }

__device__ __forceinline__ float gelu_tanh(float v) {
  float inner = 0.7978845608028654f * (v + 0.044715f * v * v * v);
  return 0.5f * v * (1.0f + tanhf(inner));
}

__device__ __forceinline__ float lin16(int i) {
  return -1.0f + (float)i * (2.0f / 15.0f);
}

// ---------------------------------------------------------------- zero scratch
__global__ __launch_bounds__(256) void k_zero(float4* __restrict__ p, unsigned n4) {
  unsigned i = blockIdx.x * 256u + threadIdx.x;
  if (i < n4) p[i] = make_float4(0.f, 0.f, 0.f, 0.f);
}

// ------------------------------------------------- split conv weights to bf16 hi/lo
// conv_w [2][2][co=64][ci=64][3][3][3] -> wh/wl [conv][off=27][co][ci]
__global__ __launch_bounds__(256) void k_prep_wt(const float* __restrict__ cw,
                                                 ush* __restrict__ wh,
                                                 ush* __restrict__ wl) {
  unsigned i = blockIdx.x * 256u + threadIdx.x;
  if (i >= 442368u) return;
  unsigned conv = i / WT_PER_CONV;
  unsigned r = i - conv * WT_PER_CONV;
  unsigned off = r >> 12;
  unsigned q = r & 4095u;
  unsigned co = q >> 6, ci = q & 63u;
  float w = cw[(conv * 4096u + co * 64u + ci) * 27u + off];
  ush hi = f2bf(w);
  wh[i] = hi;
  wl[i] = f2bf(w - bf2f(hi));
}

// ---------------------------------------------------------------- brute KNN
__global__ __launch_bounds__(256) void k_knn(const float* __restrict__ pos,
                                             int* __restrict__ idxo) {
  __shared__ float ps[NP * 3];
  int b = blockIdx.x >> 10;
  const float* pb = pos + b * NP * 3;
  for (int t = threadIdx.x; t < NP * 3; t += 256) ps[t] = pb[t];
  __syncthreads();
  int lane = threadIdx.x & 63, wave = threadIdx.x >> 6;
  int g = ((blockIdx.x & 1023) << 2) | wave;
  float gx = lin16(g >> 8), gy = lin16((g >> 4) & 15), gz = lin16(g & 15);
  float gn = gx * gx + gy * gy + gz * gz;
  ULL kk[8];
#pragma unroll
  for (int i = 0; i < 8; ++i) kk[i] = ~0ULL;
  for (int t = 0; t < 64; ++t) {
    int p = (t << 6) | lane;
    float px = ps[3 * p], py = ps[3 * p + 1], pz = ps[3 * p + 2];
    float pn = px * px + py * py + pz * pz;
    float dt = gx * px + gy * py + gz * pz;
    float d = (gn + pn) - 2.0f * dt;
    unsigned u = __float_as_uint(d);
    u ^= (unsigned)((int)u >> 31) | 0x80000000u;
    ULL key = ((ULL)u << 32) | (unsigned)p;
    if (key < kk[7]) {
      kk[7] = key;
#pragma unroll
      for (int s = 7; s >= 1; --s) {
        ULL a = kk[s - 1], c = kk[s];
        bool sw = c < a;
        kk[s - 1] = sw ? c : a;
        kk[s] = sw ? a : c;
      }
    }
  }
  ULL win = 0;
#pragma unroll
  for (int r = 0; r < 8; ++r) {
    ULL m = kk[0];
#pragma unroll
    for (int s = 1; s < 64; s <<= 1) {
      ULL o = __shfl_xor(m, s, 64);
      m = (o < m) ? o : m;
    }
    if (kk[0] == m) {
#pragma unroll
      for (int q = 0; q < 7; ++q) kk[q] = kk[q + 1];
      kk[7] = ~0ULL;
    }
    if (lane == r) win = m;
  }
  if (lane < 8) idxo[(((b << 12) | g) << 3) + lane] = (int)(win & 0xFFFFFFFFULL);
}

// -------------------------------------------------- bipartite conv + update MLP
// Writes fp32 padded vol0 (for residual) + bf16 hi/lo padded (for MFMA conv).
__global__ __launch_bounds__(256) void k_mlp(
    const float* __restrict__ pos, const float* __restrict__ xf,
    const float* __restrict__ w1, const float* __restrict__ b1,
    const float* __restrict__ w2, const float* __restrict__ b2,
    const float* __restrict__ fw, const float* __restrict__ fb,
    const float* __restrict__ uw, const float* __restrict__ ub,
    const int* __restrict__ idx, float* __restrict__ vol0,
    ush* __restrict__ v0h, ush* __restrict__ v0l) {
  int lane = threadIdx.x & 63, wave = threadIdx.x >> 6;
  float w2c[64], uwc[64];
#pragma unroll
  for (int j = 0; j < 64; ++j) w2c[j] = w2[j * 64 + lane];
#pragma unroll
  for (int j = 0; j < 64; ++j) uwc[j] = uw[j * 64 + lane];
  float w10 = w1[lane], w11 = w1[64 + lane], w12 = w1[128 + lane];
  float b1c = b1[lane], b2c = b2[lane];
  float fw0 = fw[lane], fw1 = fw[64 + lane], fw2 = fw[128 + lane], fbc = fb[lane];
  float ubc = ub[lane];
  int wg = blockIdx.x * 4 + wave;
  int b = wg >> 10;
  int g0 = (wg & 1023) * 4;
  for (int v = 0; v < 4; ++v) {
    int g = g0 + v;
    float gx = lin16(g >> 8), gy = lin16((g >> 4) & 15), gz = lin16(g & 15);
    float acc = 0.0f;
    for (int k = 0; k < 8; ++k) {
      int p = idx[(((b << 12) | g) << 3) + k];
      const float* pp = pos + (b * NP + p) * 3;
      float r0 = pp[0] - gx, r1 = pp[1] - gy, r2 = pp[2] - gz;
      float h1 = gelu_tanh(fmaf(r2, w12, fmaf(r1, w11, fmaf(r0, w10, b1c))));
      float pe = b2c;
#pragma unroll
      for (int j = 0; j < 64; ++j) {
        float hj = __uint_as_float(__builtin_amdgcn_readlane(__float_as_uint(h1), j));
        pe = fmaf(hj, w2c[j], pe);
      }
      const float* xp = xf + (b * NP + p) * 3;
      float fe = fmaf(xp[2], fw2, fmaf(xp[1], fw1, fmaf(xp[0], fw0, fbc)));
      acc = fmaf(pe, fe, acc);
    }
    acc *= 0.125f;
    float hp = ubc;
#pragma unroll
    for (int j = 0; j < 64; ++j) {
      float aj = __uint_as_float(__builtin_amdgcn_readlane(__float_as_uint(acc), j));
      hp = fmaf(aj, uwc[j], hp);
    }
    float h = gelu_tanh(hp);
    int z = g & 15, y = (g >> 4) & 15, x = g >> 8;
    int pidx = (((b * 18 + z + 1) * 18 + y + 1) * 18 + x + 1) * 64 + lane;
    vol0[pidx] = h;
    ush hi = f2bf(h);
    v0h[pidx] = hi;
    v0l[pidx] = f2bf(h - bf2f(hi));
  }
}

// ------------------------------------------- MFMA implicit-GEMM 3x3x3 conv (bf16x3)
// Block = 4 waves, 64 consecutive voxels (Z=16: 4 x-rows; Z=8: one z-slice).
// Input slab (hi+lo, padded) staged once in LDS; wave = 4 M-tiles x 1 N-tile.
// acc += Ah*Bh + Ah*Bl + Al*Bh  (fp32 accumulate; dropped Al*Bl ~ 2^-18).
template <int Z>
__global__ __launch_bounds__(256) void k_convm(const ush* __restrict__ vh,
                                               const ush* __restrict__ vl,
                                               const ush* __restrict__ wh,
                                               const ush* __restrict__ wl,
                                               float* __restrict__ out,
                                               float* __restrict__ stats) {
  constexpr int P = Z + 2;
  constexpr int Py = (Z == 16) ? 6 : 10;
  constexpr int Px = (Z == 16) ? 18 : 10;
  constexpr int NV = 3 * Py * Px;              // slab voxels (324 / 300)
  constexpr int VS = 272;                      // slab voxel stride bytes (256 + 16 pad)
  __shared__ unsigned char slab[NV * VS];
  __shared__ float ls[64], ls2[64];
  int tid = threadIdx.x;
  int lane = tid & 63, wv = tid >> 6;
  int vbase = blockIdx.x * 64;
  int b = (Z == 16) ? (vbase >> 12) : (vbase >> 9);
  int rem = vbase & (Z * Z * Z - 1);
  int z0 = rem / (Z * Z);
  int y0 = (Z == 16) ? ((rem & 255) >> 4) : 0;
  if (tid < 64) { ls[tid] = 0.0f; ls2[tid] = 0.0f; }
  // ---- stage padded slab (hi at +0, lo at +128 per voxel) ----
  {
    constexpr int NCH = NV * 8;                // 16B chunks per part
    for (int i = tid; i < NCH; i += 256) {
      int v = i >> 3, c = i & 7;
      int lz = v / (Py * Px);
      int r = v - lz * (Py * Px);
      int ly = r / Px, lx = r - ly * Px;
      int g = (((b * P + z0 + lz) * P + (y0 + ly)) * P + lx) * 64 + c * 8;
      *(uint4*)(slab + v * VS + c * 16)       = *(const uint4*)(vh + g);
      *(uint4*)(slab + v * VS + 128 + c * 16) = *(const uint4*)(vl + g);
    }
  }
  __syncthreads();
  int lm = lane & 15, quad = lane >> 4;
  int co = (wv << 4) | lm;                     // this wave's output channel
  f4v acc[4];
#pragma unroll
  for (int m = 0; m < 4; ++m) acc[m] = (f4v){0.f, 0.f, 0.f, 0.f};
  for (int off = 0; off < 27; ++off) {
    int dz = off / 9, r9 = off - dz * 9, dy = r9 / 3, dx = r9 - dy * 3;
    const ush* bph = wh + ((off * 64 + co) << 6) + (quad << 3);
    const ush* bpl = wl + ((off * 64 + co) << 6) + (quad << 3);
#pragma unroll
    for (int ks = 0; ks < 2; ++ks) {
      s8v bhf = *(const s8v*)(bph + ks * 32);
      s8v blf = *(const s8v*)(bpl + ks * 32);
#pragma unroll
      for (int m = 0; m < 4; ++m) {
        int lyp, lxp;
        if (Z == 16) { lyp = m + dy; lxp = lm + dx; }
        else         { lyp = 2 * m + (lm >> 3) + dy; lxp = (lm & 7) + dx; }
        int sv = (dz * Py + lyp) * Px + lxp;
        const unsigned char* ap = slab + sv * VS + (quad << 4) + (ks << 6);
        s8v ahf = *(const s8v*)(ap);
        s8v alf = *(const s8v*)(ap + 128);
        acc[m] = __builtin_amdgcn_mfma_f32_16x16x32_bf16(ahf, bhf, acc[m], 0, 0, 0);
        acc[m] = __builtin_amdgcn_mfma_f32_16x16x32_bf16(ahf, blf, acc[m], 0, 0, 0);
        acc[m] = __builtin_amdgcn_mfma_f32_16x16x32_bf16(alf, bhf, acc[m], 0, 0, 0);
      }
    }
  }
  // ---- store (D: row m = quad*4+r, col = lm) + BN stats ----
  float s = 0.0f, s2 = 0.0f;
#pragma unroll
  for (int m = 0; m < 4; ++m) {
    int vx = vbase + (m << 4) + (quad << 2);
#pragma unroll
    for (int r = 0; r < 4; ++r) {
      float v = acc[m][r];
      out[(vx + r) * 64 + co] = v;
      s += v;
      s2 = fmaf(v, v, s2);
    }
  }
  atomicAdd(&ls[co], s);
  atomicAdd(&ls2[co], s2);
  __syncthreads();
  if (tid < 64) {
    atomicAdd(&stats[tid * 2], ls[tid]);
    atomicAdd(&stats[tid * 2 + 1], ls2[tid]);
  }
}

// ------------------------------------ relu(bn(x)) -> padded bf16 hi/lo volumes
template <int Z>
__global__ __launch_bounds__(256) void k_bnrelu(const float* __restrict__ t,
                                                const float* __restrict__ stats,
                                                ush* __restrict__ outh,
                                                ush* __restrict__ outl,
                                                float inv_cnt) {
  constexpr int P = Z + 2;
  unsigned i = blockIdx.x * 256u + threadIdx.x;
  int c = i & 63;
  int vox = i >> 6;
  int x = vox % Z;
  int q = vox / Z;
  int y = q % Z;
  q /= Z;
  int z = q % Z;
  int b = q / Z;
  float m = stats[c * 2] * inv_cnt;
  float var = stats[c * 2 + 1] * inv_cnt - m * m;
  float rs = 1.0f / sqrtf(var + EPSF);
  float v = (t[i] - m) * rs;
  v = v > 0.0f ? v : 0.0f;
  int pidx = (((b * P + z + 1) * P + y + 1) * P + x + 1) * 64 + c;
  ush hi = f2bf(v);
  outh[pidx] = hi;
  outl[pidx] = f2bf(v - bf2f(hi));
}

// --------------------------------- vol = relu(vol0 + bn(t2)) then 2x2x2 maxpool
__global__ __launch_bounds__(256) void k_residpool(const float* __restrict__ vol0,
                                                   const float* __restrict__ t2,
                                                   const float* __restrict__ stats,
                                                   float* __restrict__ vol1,
                                                   ush* __restrict__ v1h,
                                                   ush* __restrict__ v1l) {
  unsigned i = blockIdx.x * 256u + threadIdx.x;  // < 131072
  int c = i & 63;
  int pv = i >> 6;
  int xp = pv & 7, yp = (pv >> 3) & 7, zp = (pv >> 6) & 7, b = pv >> 9;
  float m = stats[c * 2] * (1.0f / 16384.0f);
  float var = stats[c * 2 + 1] * (1.0f / 16384.0f) - m * m;
  float rs = 1.0f / sqrtf(var + EPSF);
  float best = 0.0f;
  for (int dz = 0; dz < 2; ++dz)
    for (int dy = 0; dy < 2; ++dy)
      for (int dx = 0; dx < 2; ++dx) {
        int z = 2 * zp + dz, y = 2 * yp + dy, x = 2 * xp + dx;
        float a = vol0[(((b * 18 + z + 1) * 18 + y + 1) * 18 + x + 1) * 64 + c];
        float t = t2[(b * 4096 + z * 256 + y * 16 + x) * 64 + c];
        float u = a + (t - m) * rs;
        u = u > 0.0f ? u : 0.0f;
        best = u > best ? u : best;
      }
  int pidx = (((b * 10 + zp + 1) * 10 + yp + 1) * 10 + xp + 1) * 64 + c;
  vol1[pidx] = best;
  ush hi = f2bf(best);
  v1h[pidx] = hi;
  v1l[pidx] = f2bf(best - bf2f(hi));
}

// -------------------- vol2 = relu(vol1 + bn(t4)); only its BN stats are needed
__global__ __launch_bounds__(256) void k_resid2(const float* __restrict__ vol1,
                                                const float* __restrict__ t4,
                                                const float* __restrict__ stats,
                                                float* __restrict__ sF,
                                                float* __restrict__ sB) {
  __shared__ float ls[64], ls2[64];
  if (threadIdx.x < 64) { ls[threadIdx.x] = 0.0f; ls2[threadIdx.x] = 0.0f; }
  __syncthreads();
  unsigned i = blockIdx.x * 256u + threadIdx.x;  // < 131072
  int c = i & 63;
  int pv = i >> 6;
  int x = pv & 7, y = (pv >> 3) & 7, z = (pv >> 6) & 7, b = pv >> 9;
  float m = stats[c * 2] * (1.0f / 2048.0f);
  float var = stats[c * 2 + 1] * (1.0f / 2048.0f) - m * m;
  float rs = 1.0f / sqrtf(var + EPSF);
  float a = vol1[(((b * 10 + z + 1) * 10 + y + 1) * 10 + x + 1) * 64 + c];
  float u = a + (t4[i] - m) * rs;
  u = u > 0.0f ? u : 0.0f;
  atomicAdd(&ls[c], u);
  atomicAdd(&ls2[c], u * u);
  __syncthreads();
  if (threadIdx.x < 64) {
    int cc = threadIdx.x;
    atomicAdd(&sF[cc * 2], ls[cc]);
    atomicAdd(&sF[cc * 2 + 1], ls2[cc]);
    atomicAdd(&sB[b * 64 + cc], ls[cc]);
  }
}

// ------------- final bn affine + spatial mean pool + linear head -> [4,16]
__global__ __launch_bounds__(64) void k_final(const float* __restrict__ sF,
                                              const float* __restrict__ sB,
                                              const float* __restrict__ ong,
                                              const float* __restrict__ onb,
                                              const float* __restrict__ row,
                                              const float* __restrict__ rob,
                                              float* __restrict__ outp) {
  __shared__ float pl[4][64];
  int c = threadIdx.x;
  float m = sF[c * 2] * (1.0f / 2048.0f);
  float var = sF[c * 2 + 1] * (1.0f / 2048.0f) - m * m;
  float rs = 1.0f / sqrtf(var + EPSF);
  float gg = ong[c], bb = onb[c];
  for (int b = 0; b < 4; ++b)
    pl[b][c] = (sB[b * 64 + c] * (1.0f / 512.0f) - m) * rs * gg + bb;
  __syncthreads();
  int b = threadIdx.x >> 4, o = threadIdx.x & 15;
  float s = rob[o];
  for (int j = 0; j < 64; ++j) s = fmaf(pl[b][j], row[j * 16 + o], s);
  outp[b * 16 + o] = s;
}

extern "C" void kernel_launch(void* const* d_in, const int* in_sizes, int n_in,
                              void* d_out, int out_size, void* d_ws, size_t ws_size,
                              hipStream_t stream) {
  (void)in_sizes; (void)n_in; (void)out_size; (void)ws_size;
  const float* pos = (const float*)d_in[0];
  const float* xf  = (const float*)d_in[1];
  const float* pw1 = (const float*)d_in[2];
  const float* pb1 = (const float*)d_in[3];
  const float* pw2 = (const float*)d_in[4];
  const float* pb2 = (const float*)d_in[5];
  const float* fw  = (const float*)d_in[6];
  const float* fb  = (const float*)d_in[7];
  const float* uw  = (const float*)d_in[8];
  const float* ubp = (const float*)d_in[9];
  const float* cw  = (const float*)d_in[10];
  // d_in[11] = conv_b: unused (training-mode BN cancels conv bias exactly)
  const float* ong = (const float*)d_in[12];
  const float* onb = (const float*)d_in[13];
  const float* row = (const float*)d_in[14];
  const float* rob = (const float*)d_in[15];

  float* ws   = (float*)d_ws;
  ush*   wh   = (ush*)(ws + WH_OFF);
  ush*   wl   = (ush*)(ws + WL_OFF);
  int*   idx  = (int*)(ws + IDX_OFF);
  float* vol0 = ws + VOL0_OFF;
  ush*   v0h  = (ush*)(ws + V0H_OFF);   // also a1 hi
  ush*   v0l  = (ush*)(ws + V0L_OFF);   // also a1 lo
  float* t1   = ws + T1_OFF;            // also t2
  float* vol1 = ws + VOL1_OFF;
  ush*   v1h  = (ush*)(ws + V1H_OFF);   // also a3 hi
  ush*   v1l  = (ush*)(ws + V1L_OFF);   // also a3 lo
  float* t3   = ws + T3_OFF;            // also t4
  float* sA   = ws + STATS_OFF;
  float* sF   = sA + 512;
  float* sB   = sF + 128;

  // zero bf16 padded vols (halos!) + stats (ws poisoned 0xAA each call)
  k_zero<<<1458, 256, 0, stream>>>((float4*)(ws + V0H_OFF), 373248u);
  k_zero<<<250, 256, 0, stream>>>((float4*)(ws + V1H_OFF), 64000u);
  k_zero<<<1, 256, 0, stream>>>((float4*)(ws + STATS_OFF), 224u);
  k_prep_wt<<<1728, 256, 0, stream>>>(cw, wh, wl);
  k_knn<<<4096, 256, 0, stream>>>(pos, idx);
  k_mlp<<<1024, 256, 0, stream>>>(pos, xf, pw1, pb1, pw2, pb2, fw, fb, uw, ubp, idx,
                                  vol0, v0h, v0l);
  // block 0 (16^3)
  k_convm<16><<<256, 256, 0, stream>>>(v0h, v0l, wh, wl, t1, sA);
  k_bnrelu<16><<<4096, 256, 0, stream>>>(t1, sA, v0h, v0l, 1.0f / 16384.0f); // a1
  k_convm<16><<<256, 256, 0, stream>>>(v0h, v0l, wh + WT_PER_CONV, wl + WT_PER_CONV,
                                       t1, sA + 128);                        // t2
  k_residpool<<<512, 256, 0, stream>>>(vol0, t1, sA + 128, vol1, v1h, v1l);
  // block 1 (8^3)
  k_convm<8><<<32, 256, 0, stream>>>(v1h, v1l, wh + 2 * WT_PER_CONV,
                                     wl + 2 * WT_PER_CONV, t3, sA + 256);
  k_bnrelu<8><<<512, 256, 0, stream>>>(t3, sA + 256, v1h, v1l, 1.0f / 2048.0f); // a3
  k_convm<8><<<32, 256, 0, stream>>>(v1h, v1l, wh + 3 * WT_PER_CONV,
                                     wl + 3 * WT_PER_CONV, t3, sA + 384);       // t4
  k_resid2<<<512, 256, 0, stream>>>(vol1, t3, sA + 384, sF, sB);
  // head
  k_final<<<1, 64, 0, stream>>>(sF, sB, ong, onb, row, rob, (float*)d_out);
}

// Round 4
// 372.414 us; speedup vs baseline: 2.7981x; 1.1849x over previous
//
#include <hip/hip_runtime.h>

#define ULL unsigned long long
typedef unsigned short ush;
typedef __attribute__((ext_vector_type(8))) short s8v;   // 8 bf16 (4 VGPRs)
typedef __attribute__((ext_vector_type(4))) float f4v;   // MFMA accumulator

// problem constants
#define BB 4
#define NP 4096
#define HH 64
#define EPSF 1e-5f

// workspace float offsets (ws is float*)
#define WH_OFF      0u           // [4][27][64][64] bf16 hi = 442368 bf16 = 221184 f
#define WL_OFF      221184u      // lo part
#define WT_PER_CONV 110592u      // bf16 elements per conv
#define IDX_OFF     442368u      // B*G*8 ints = 131072
#define VOL0_OFF    573440u      // fp32 padded [4][18][18][18][64] = 1492992 f
#define V0H_OFF     2066432u     // bf16 padded hi = 746496 f   } reused as a1 hi
#define V0L_OFF     2812928u     // bf16 padded lo = 746496 f   } reused as a1 lo
#define T1_OFF      3559424u     // fp32 [4][16][16][16][64] = 1048576 f (reused as t2)
#define VOL1_OFF    4608000u     // fp32 padded [4][10][10][10][64] = 256000 f
#define V1H_OFF     4864000u     // 128000 f  } reused as a3 hi
#define V1L_OFF     4992000u     // 128000 f  } reused as a3 lo
#define T3_OFF      5120000u     // fp32 [4][8][8][8][64] = 131072 f (reused as t4)
#define STATS_OFF   5251072u     // sA[4][128], sF[128], sB[4][64] = 896 f
#define CELLS_OFF   5251968u     // cellStart: 4 x 4097 ints (padded to 16400)
#define SPOS_OFF    5268368u     // sortedPos: 4 x 4096 float4 = 65536 f (16B aligned)

// merged zero ranges (float4 counts)
#define ZN_V0   373248u          // [V0H, T1)
#define ZN_V1   64000u           // [V1H, T3)
#define ZN_ST   224u             // stats
#define ZN_ALL  (ZN_V0 + ZN_V1 + ZN_ST)

__device__ __forceinline__ ush f2bf(float f) {            // fp32 -> bf16 RNE
  unsigned u = __float_as_uint(f);
  return (ush)((u + 0x7FFFu + ((u >> 16) & 1u)) >> 16);
}
__device__ __forceinline__ float bf2f(ush h) { return __uint_as_float(((unsigned)h) << 16); }

__device__ __forceinline__ float gelu_tanh(float v) {
  float inner = 0.7978845608028654f * (v + 0.044715f * v * v * v);
  return 0.5f * v * (1.0f + tanhf(inner));
}

__device__ __forceinline__ float lin16(int i) {
  return -1.0f + (float)i * (2.0f / 15.0f);
}

// ---------------------------------------------------------------- zero scratch
__global__ __launch_bounds__(256) void k_zeroall(float* __restrict__ ws) {
  unsigned i = blockIdx.x * 256u + threadIdx.x;
  float4 z = make_float4(0.f, 0.f, 0.f, 0.f);
  if (i < ZN_V0) ((float4*)(ws + V0H_OFF))[i] = z;
  else if (i < ZN_V0 + ZN_V1) ((float4*)(ws + V1H_OFF))[i - ZN_V0] = z;
  else if (i < ZN_ALL) ((float4*)(ws + STATS_OFF))[i - ZN_V0 - ZN_V1] = z;
}

// ------------------------------------------------- split conv weights to bf16 hi/lo
// conv_w [2][2][co=64][ci=64][3][3][3] -> wh/wl [conv][off=27][co][ci]
__global__ __launch_bounds__(256) void k_prep_wt(const float* __restrict__ cw,
                                                 ush* __restrict__ wh,
                                                 ush* __restrict__ wl) {
  unsigned i = blockIdx.x * 256u + threadIdx.x;
  if (i >= 442368u) return;
  unsigned conv = i / WT_PER_CONV;
  unsigned r = i - conv * WT_PER_CONV;
  unsigned off = r >> 12;
  unsigned q = r & 4095u;
  unsigned co = q >> 6, ci = q & 63u;
  float w = cw[(conv * 4096u + co * 64u + ci) * 27u + off];
  ush hi = f2bf(w);
  wh[i] = hi;
  wl[i] = f2bf(w - bf2f(hi));
}

// ------------------------------------------------- bin points to nearest voxel cell
// one block per batch: LDS histogram -> block prefix scan -> scatter.
// cellStart[b][4097] (global), sortedPos[b][4096] = {x,y,z,bitcast(idx)}.
__global__ __launch_bounds__(256) void k_bin(const float* __restrict__ pos,
                                             int* __restrict__ cellStart,
                                             float4* __restrict__ sortedPos) {
  __shared__ int cnt[4096];
  __shared__ int wsum[4];
  int tid = threadIdx.x;
  int b = blockIdx.x;
  const float* pb = pos + b * NP * 3;
  for (int i = tid; i < 4096; i += 256) cnt[i] = 0;
  __syncthreads();
#pragma unroll
  for (int t = 0; t < 16; ++t) {
    int p = t * 256 + tid;
    float px = pb[3 * p], py = pb[3 * p + 1], pz = pb[3 * p + 2];
    int c0 = (int)floorf((px + 1.0f) * 7.5f + 0.5f);
    int c1 = (int)floorf((py + 1.0f) * 7.5f + 0.5f);
    int c2 = (int)floorf((pz + 1.0f) * 7.5f + 0.5f);
    c0 = min(max(c0, 0), 15); c1 = min(max(c1, 0), 15); c2 = min(max(c2, 0), 15);
    atomicAdd(&cnt[(c0 * 16 + c1) * 16 + c2], 1);
  }
  __syncthreads();
  // exclusive scan over 4096 cells; thread owns cells [tid*16, tid*16+16)
  int base = tid * 16;
  int loc[16];
  int run = 0;
#pragma unroll
  for (int j = 0; j < 16; ++j) { loc[j] = run; run += cnt[base + j]; }
  int lane = tid & 63, wv = tid >> 6;
  int inc = run;
  for (int d = 1; d < 64; d <<= 1) {
    int o = __shfl_up(inc, d, 64);
    if (lane >= d) inc += o;
  }
  if (lane == 63) wsum[wv] = inc;
  __syncthreads();
  int woff = 0;
  for (int w = 0; w < wv; ++w) woff += wsum[w];
  int excl = woff + inc - run;
  __syncthreads();                               // cnt reads done; safe to overwrite
  int stv[16];
#pragma unroll
  for (int j = 0; j < 16; ++j) {
    stv[j] = excl + loc[j];
    cellStart[b * 4097 + base + j] = stv[j];
  }
#pragma unroll
  for (int j = 0; j < 16; ++j) cnt[base + j] = stv[j];
  if (tid == 0) cellStart[b * 4097 + 4096] = NP;
  __syncthreads();
#pragma unroll
  for (int t = 0; t < 16; ++t) {
    int p = t * 256 + tid;
    float px = pb[3 * p], py = pb[3 * p + 1], pz = pb[3 * p + 2];
    int c0 = (int)floorf((px + 1.0f) * 7.5f + 0.5f);
    int c1 = (int)floorf((py + 1.0f) * 7.5f + 0.5f);
    int c2 = (int)floorf((pz + 1.0f) * 7.5f + 0.5f);
    c0 = min(max(c0, 0), 15); c1 = min(max(c1, 0), 15); c2 = min(max(c2, 0), 15);
    int slot = atomicAdd(&cnt[(c0 * 16 + c1) * 16 + c2], 1);
    sortedPos[b * 4096 + slot] = make_float4(px, py, pz, __int_as_float(p));
  }
}

// ------------------------------------------------- binned exact KNN (top-8)
// thread per voxel; expanding Chebyshev shells over cells; provable stop when
// ((s+0.5)h - eps)^2 exceeds current 8th distance. Exact (dist,idx) key order.
__global__ __launch_bounds__(64) void k_knn2(const int* __restrict__ cellStart,
                                             const float4* __restrict__ sortedPos,
                                             int* __restrict__ idxo) {
  __shared__ int cs[4097];
  int tid = threadIdx.x;
  int vox = blockIdx.x * 64 + tid;               // 16384 voxels
  int b = vox >> 12;
  int g = vox & 4095;
  for (int i = tid; i < 4097; i += 64) cs[i] = cellStart[b * 4097 + i];
  __syncthreads();
  int ii = g >> 8, jj = (g >> 4) & 15, kkc = g & 15;
  float gx = lin16(ii), gy = lin16(jj), gz = lin16(kkc);
  float gn = gx * gx + gy * gy + gz * gz;
  const float4* sp = sortedPos + b * 4096;
  ULL kk[8];
#pragma unroll
  for (int q = 0; q < 8; ++q) kk[q] = ~0ULL;
  for (int s = 0; s < 16; ++s) {
    int alo = max(ii - s, 0), ahi = min(ii + s, 15);
    int blo = max(jj - s, 0), bhi = min(jj + s, 15);
    int clo = max(kkc - s, 0), chi = min(kkc + s, 15);
    for (int a = alo; a <= ahi; ++a)
      for (int b2 = blo; b2 <= bhi; ++b2) {
        bool edge = (a == ii - s) || (a == ii + s) || (b2 == jj - s) || (b2 == jj + s);
        int cbase = (a * 16 + b2) * 16;
        int r0lo, r0hi, r1lo, r1hi;
        if (edge) { r0lo = clo; r0hi = chi; r1lo = 1; r1hi = 0; }
        else {
          r0lo = kkc - s; r0hi = (kkc - s >= 0) ? kkc - s : kkc - s - 1; // valid iff >=0
          if (kkc - s < 0) { r0lo = 1; r0hi = 0; }
          r1lo = kkc + s; r1hi = (kkc + s <= 15) ? kkc + s : kkc + s - 1;
          if (kkc + s > 15) { r1lo = 1; r1hi = 0; }
        }
#pragma unroll
        for (int rr = 0; rr < 2; ++rr) {
          int rlo = rr ? r1lo : r0lo, rhi = rr ? r1hi : r0hi;
          if (rlo > rhi) continue;
          int st = cs[cbase + rlo], en = cs[cbase + rhi + 1];
          for (int t = st; t < en; ++t) {
            float4 c = sp[t];
            float px = c.x, py = c.y, pz = c.z;
            float pn = px * px + py * py + pz * pz;
            float dt = gx * px + gy * py + gz * pz;
            float d = (gn + pn) - 2.0f * dt;
            unsigned u = __float_as_uint(d);
            u ^= (unsigned)((int)u >> 31) | 0x80000000u;
            ULL key = ((ULL)u << 32) | (unsigned)__float_as_uint(c.w);
            if (key < kk[7]) {
              kk[7] = key;
#pragma unroll
              for (int q2 = 7; q2 >= 1; --q2) {
                ULL x0 = kk[q2 - 1], x1 = kk[q2];
                bool sw = x1 < x0;
                kk[q2 - 1] = sw ? x1 : x0;
                kk[q2] = sw ? x0 : x1;
              }
            }
          }
        }
      }
    float bnd = ((float)s + 0.5f) * (2.0f / 15.0f) - 1e-5f;
    float b2f = bnd * bnd;
    unsigned ub = __float_as_uint(b2f) | 0x80000000u;
    if (((ULL)ub << 32) > kk[7]) break;          // strict: safe for exact ties
  }
#pragma unroll
  for (int q = 0; q < 8; ++q)
    idxo[(((b << 12) | g) << 3) + q] = (int)(kk[q] & 0xFFFFFFFFULL);
}

// -------------------------------------------------- bipartite conv + update MLP
// Writes fp32 padded vol0 (for residual) + bf16 hi/lo padded (for MFMA conv).
__global__ __launch_bounds__(256) void k_mlp(
    const float* __restrict__ pos, const float* __restrict__ xf,
    const float* __restrict__ w1, const float* __restrict__ b1,
    const float* __restrict__ w2, const float* __restrict__ b2,
    const float* __restrict__ fw, const float* __restrict__ fb,
    const float* __restrict__ uw, const float* __restrict__ ub,
    const int* __restrict__ idx, float* __restrict__ vol0,
    ush* __restrict__ v0h, ush* __restrict__ v0l) {
  int lane = threadIdx.x & 63, wave = threadIdx.x >> 6;
  float w2c[64], uwc[64];
#pragma unroll
  for (int j = 0; j < 64; ++j) w2c[j] = w2[j * 64 + lane];
#pragma unroll
  for (int j = 0; j < 64; ++j) uwc[j] = uw[j * 64 + lane];
  float w10 = w1[lane], w11 = w1[64 + lane], w12 = w1[128 + lane];
  float b1c = b1[lane], b2c = b2[lane];
  float fw0 = fw[lane], fw1 = fw[64 + lane], fw2 = fw[128 + lane], fbc = fb[lane];
  float ubc = ub[lane];
  int wg = blockIdx.x * 4 + wave;
  int b = wg >> 10;
  int g0 = (wg & 1023) * 4;
  for (int v = 0; v < 4; ++v) {
    int g = g0 + v;
    float gx = lin16(g >> 8), gy = lin16((g >> 4) & 15), gz = lin16(g & 15);
    float acc = 0.0f;
    for (int k = 0; k < 8; ++k) {
      int p = idx[(((b << 12) | g) << 3) + k];
      const float* pp = pos + (b * NP + p) * 3;
      float r0 = pp[0] - gx, r1 = pp[1] - gy, r2 = pp[2] - gz;
      float h1 = gelu_tanh(fmaf(r2, w12, fmaf(r1, w11, fmaf(r0, w10, b1c))));
      float pe = b2c;
#pragma unroll
      for (int j = 0; j < 64; ++j) {
        float hj = __uint_as_float(__builtin_amdgcn_readlane(__float_as_uint(h1), j));
        pe = fmaf(hj, w2c[j], pe);
      }
      const float* xp = xf + (b * NP + p) * 3;
      float fe = fmaf(xp[2], fw2, fmaf(xp[1], fw1, fmaf(xp[0], fw0, fbc)));
      acc = fmaf(pe, fe, acc);
    }
    acc *= 0.125f;
    float hp = ubc;
#pragma unroll
    for (int j = 0; j < 64; ++j) {
      float aj = __uint_as_float(__builtin_amdgcn_readlane(__float_as_uint(acc), j));
      hp = fmaf(aj, uwc[j], hp);
    }
    float h = gelu_tanh(hp);
    int z = g & 15, y = (g >> 4) & 15, x = g >> 8;
    int pidx = (((b * 18 + z + 1) * 18 + y + 1) * 18 + x + 1) * 64 + lane;
    vol0[pidx] = h;
    ush hi = f2bf(h);
    v0h[pidx] = hi;
    v0l[pidx] = f2bf(h - bf2f(hi));
  }
}

// ------------------------------------------- MFMA implicit-GEMM 3x3x3 conv (bf16x3)
// Block = 4 waves, 64 consecutive voxels (Z=16: 4 x-rows; Z=8: one z-slice).
// Input slab (hi+lo, padded) staged once in LDS; wave = 4 M-tiles x 1 N-tile.
// acc += Ah*Bh + Ah*Bl + Al*Bh  (fp32 accumulate; dropped Al*Bl ~ 2^-18).
template <int Z>
__global__ __launch_bounds__(256) void k_convm(const ush* __restrict__ vh,
                                               const ush* __restrict__ vl,
                                               const ush* __restrict__ wh,
                                               const ush* __restrict__ wl,
                                               float* __restrict__ out,
                                               float* __restrict__ stats) {
  constexpr int P = Z + 2;
  constexpr int Py = (Z == 16) ? 6 : 10;
  constexpr int Px = (Z == 16) ? 18 : 10;
  constexpr int NV = 3 * Py * Px;              // slab voxels (324 / 300)
  constexpr int VS = 272;                      // slab voxel stride bytes (256 + 16 pad)
  __shared__ unsigned char slab[NV * VS];
  __shared__ float ls[64], ls2[64];
  int tid = threadIdx.x;
  int lane = tid & 63, wv = tid >> 6;
  int vbase = blockIdx.x * 64;
  int b = (Z == 16) ? (vbase >> 12) : (vbase >> 9);
  int rem = vbase & (Z * Z * Z - 1);
  int z0 = rem / (Z * Z);
  int y0 = (Z == 16) ? ((rem & 255) >> 4) : 0;
  if (tid < 64) { ls[tid] = 0.0f; ls2[tid] = 0.0f; }
  // ---- stage padded slab (hi at +0, lo at +128 per voxel) ----
  {
    constexpr int NCH = NV * 8;                // 16B chunks per part
    for (int i = tid; i < NCH; i += 256) {
      int v = i >> 3, c = i & 7;
      int lz = v / (Py * Px);
      int r = v - lz * (Py * Px);
      int ly = r / Px, lx = r - ly * Px;
      int g = (((b * P + z0 + lz) * P + (y0 + ly)) * P + lx) * 64 + c * 8;
      *(uint4*)(slab + v * VS + c * 16)       = *(const uint4*)(vh + g);
      *(uint4*)(slab + v * VS + 128 + c * 16) = *(const uint4*)(vl + g);
    }
  }
  __syncthreads();
  int lm = lane & 15, quad = lane >> 4;
  int co = (wv << 4) | lm;                     // this wave's output channel
  f4v acc[4];
#pragma unroll
  for (int m = 0; m < 4; ++m) acc[m] = (f4v){0.f, 0.f, 0.f, 0.f};
  for (int off = 0; off < 27; ++off) {
    int dz = off / 9, r9 = off - dz * 9, dy = r9 / 3, dx = r9 - dy * 3;
    const ush* bph = wh + ((off * 64 + co) << 6) + (quad << 3);
    const ush* bpl = wl + ((off * 64 + co) << 6) + (quad << 3);
#pragma unroll
    for (int ks = 0; ks < 2; ++ks) {
      s8v bhf = *(const s8v*)(bph + ks * 32);
      s8v blf = *(const s8v*)(bpl + ks * 32);
#pragma unroll
      for (int m = 0; m < 4; ++m) {
        int lyp, lxp;
        if (Z == 16) { lyp = m + dy; lxp = lm + dx; }
        else         { lyp = 2 * m + (lm >> 3) + dy; lxp = (lm & 7) + dx; }
        int sv = (dz * Py + lyp) * Px + lxp;
        const unsigned char* ap = slab + sv * VS + (quad << 4) + (ks << 6);
        s8v ahf = *(const s8v*)(ap);
        s8v alf = *(const s8v*)(ap + 128);
        acc[m] = __builtin_amdgcn_mfma_f32_16x16x32_bf16(ahf, bhf, acc[m], 0, 0, 0);
        acc[m] = __builtin_amdgcn_mfma_f32_16x16x32_bf16(ahf, blf, acc[m], 0, 0, 0);
        acc[m] = __builtin_amdgcn_mfma_f32_16x16x32_bf16(alf, bhf, acc[m], 0, 0, 0);
      }
    }
  }
  // ---- store (D: row m = quad*4+r, col = lm) + BN stats ----
  float s = 0.0f, s2 = 0.0f;
#pragma unroll
  for (int m = 0; m < 4; ++m) {
    int vx = vbase + (m << 4) + (quad << 2);
#pragma unroll
    for (int r = 0; r < 4; ++r) {
      float v = acc[m][r];
      out[(vx + r) * 64 + co] = v;
      s += v;
      s2 = fmaf(v, v, s2);
    }
  }
  atomicAdd(&ls[co], s);
  atomicAdd(&ls2[co], s2);
  __syncthreads();
  if (tid < 64) {
    atomicAdd(&stats[tid * 2], ls[tid]);
    atomicAdd(&stats[tid * 2 + 1], ls2[tid]);
  }
}

// ------------------------------------ relu(bn(x)) -> padded bf16 hi/lo volumes
template <int Z>
__global__ __launch_bounds__(256) void k_bnrelu(const float* __restrict__ t,
                                                const float* __restrict__ stats,
                                                ush* __restrict__ outh,
                                                ush* __restrict__ outl,
                                                float inv_cnt) {
  constexpr int P = Z + 2;
  unsigned i = blockIdx.x * 256u + threadIdx.x;
  int c = i & 63;
  int vox = i >> 6;
  int x = vox % Z;
  int q = vox / Z;
  int y = q % Z;
  q /= Z;
  int z = q % Z;
  int b = q / Z;
  float m = stats[c * 2] * inv_cnt;
  float var = stats[c * 2 + 1] * inv_cnt - m * m;
  float rs = 1.0f / sqrtf(var + EPSF);
  float v = (t[i] - m) * rs;
  v = v > 0.0f ? v : 0.0f;
  int pidx = (((b * P + z + 1) * P + y + 1) * P + x + 1) * 64 + c;
  ush hi = f2bf(v);
  outh[pidx] = hi;
  outl[pidx] = f2bf(v - bf2f(hi));
}

// --------------------------------- vol = relu(vol0 + bn(t2)) then 2x2x2 maxpool
__global__ __launch_bounds__(256) void k_residpool(const float* __restrict__ vol0,
                                                   const float* __restrict__ t2,
                                                   const float* __restrict__ stats,
                                                   float* __restrict__ vol1,
                                                   ush* __restrict__ v1h,
                                                   ush* __restrict__ v1l) {
  unsigned i = blockIdx.x * 256u + threadIdx.x;  // < 131072
  int c = i & 63;
  int pv = i >> 6;
  int xp = pv & 7, yp = (pv >> 3) & 7, zp = (pv >> 6) & 7, b = pv >> 9;
  float m = stats[c * 2] * (1.0f / 16384.0f);
  float var = stats[c * 2 + 1] * (1.0f / 16384.0f) - m * m;
  float rs = 1.0f / sqrtf(var + EPSF);
  float best = 0.0f;
  for (int dz = 0; dz < 2; ++dz)
    for (int dy = 0; dy < 2; ++dy)
      for (int dx = 0; dx < 2; ++dx) {
        int z = 2 * zp + dz, y = 2 * yp + dy, x = 2 * xp + dx;
        float a = vol0[(((b * 18 + z + 1) * 18 + y + 1) * 18 + x + 1) * 64 + c];
        float t = t2[(b * 4096 + z * 256 + y * 16 + x) * 64 + c];
        float u = a + (t - m) * rs;
        u = u > 0.0f ? u : 0.0f;
        best = u > best ? u : best;
      }
  int pidx = (((b * 10 + zp + 1) * 10 + yp + 1) * 10 + xp + 1) * 64 + c;
  vol1[pidx] = best;
  ush hi = f2bf(best);
  v1h[pidx] = hi;
  v1l[pidx] = f2bf(best - bf2f(hi));
}

// -------------------- vol2 = relu(vol1 + bn(t4)); only its BN stats are needed
__global__ __launch_bounds__(256) void k_resid2(const float* __restrict__ vol1,
                                                const float* __restrict__ t4,
                                                const float* __restrict__ stats,
                                                float* __restrict__ sF,
                                                float* __restrict__ sB) {
  __shared__ float ls[64], ls2[64];
  if (threadIdx.x < 64) { ls[threadIdx.x] = 0.0f; ls2[threadIdx.x] = 0.0f; }
  __syncthreads();
  unsigned i = blockIdx.x * 256u + threadIdx.x;  // < 131072
  int c = i & 63;
  int pv = i >> 6;
  int x = pv & 7, y = (pv >> 3) & 7, z = (pv >> 6) & 7, b = pv >> 9;
  float m = stats[c * 2] * (1.0f / 2048.0f);
  float var = stats[c * 2 + 1] * (1.0f / 2048.0f) - m * m;
  float rs = 1.0f / sqrtf(var + EPSF);
  float a = vol1[(((b * 10 + z + 1) * 10 + y + 1) * 10 + x + 1) * 64 + c];
  float u = a + (t4[i] - m) * rs;
  u = u > 0.0f ? u : 0.0f;
  atomicAdd(&ls[c], u);
  atomicAdd(&ls2[c], u * u);
  __syncthreads();
  if (threadIdx.x < 64) {
    int cc = threadIdx.x;
    atomicAdd(&sF[cc * 2], ls[cc]);
    atomicAdd(&sF[cc * 2 + 1], ls2[cc]);
    atomicAdd(&sB[b * 64 + cc], ls[cc]);
  }
}

// ------------- final bn affine + spatial mean pool + linear head -> [4,16]
__global__ __launch_bounds__(64) void k_final(const float* __restrict__ sF,
                                              const float* __restrict__ sB,
                                              const float* __restrict__ ong,
                                              const float* __restrict__ onb,
                                              const float* __restrict__ row,
                                              const float* __restrict__ rob,
                                              float* __restrict__ outp) {
  __shared__ float pl[4][64];
  int c = threadIdx.x;
  float m = sF[c * 2] * (1.0f / 2048.0f);
  float var = sF[c * 2 + 1] * (1.0f / 2048.0f) - m * m;
  float rs = 1.0f / sqrtf(var + EPSF);
  float gg = ong[c], bb = onb[c];
  for (int b = 0; b < 4; ++b)
    pl[b][c] = (sB[b * 64 + c] * (1.0f / 512.0f) - m) * rs * gg + bb;
  __syncthreads();
  int b = threadIdx.x >> 4, o = threadIdx.x & 15;
  float s = rob[o];
  for (int j = 0; j < 64; ++j) s = fmaf(pl[b][j], row[j * 16 + o], s);
  outp[b * 16 + o] = s;
}

extern "C" void kernel_launch(void* const* d_in, const int* in_sizes, int n_in,
                              void* d_out, int out_size, void* d_ws, size_t ws_size,
                              hipStream_t stream) {
  (void)in_sizes; (void)n_in; (void)out_size; (void)ws_size;
  const float* pos = (const float*)d_in[0];
  const float* xf  = (const float*)d_in[1];
  const float* pw1 = (const float*)d_in[2];
  const float* pb1 = (const float*)d_in[3];
  const float* pw2 = (const float*)d_in[4];
  const float* pb2 = (const float*)d_in[5];
  const float* fw  = (const float*)d_in[6];
  const float* fb  = (const float*)d_in[7];
  const float* uw  = (const float*)d_in[8];
  const float* ubp = (const float*)d_in[9];
  const float* cw  = (const float*)d_in[10];
  // d_in[11] = conv_b: unused (training-mode BN cancels conv bias exactly)
  const float* ong = (const float*)d_in[12];
  const float* onb = (const float*)d_in[13];
  const float* row = (const float*)d_in[14];
  const float* rob = (const float*)d_in[15];

  float* ws   = (float*)d_ws;
  ush*   wh   = (ush*)(ws + WH_OFF);
  ush*   wl   = (ush*)(ws + WL_OFF);
  int*   idx  = (int*)(ws + IDX_OFF);
  float* vol0 = ws + VOL0_OFF;
  ush*   v0h  = (ush*)(ws + V0H_OFF);   // also a1 hi
  ush*   v0l  = (ush*)(ws + V0L_OFF);   // also a1 lo
  float* t1   = ws + T1_OFF;            // also t2
  float* vol1 = ws + VOL1_OFF;
  ush*   v1h  = (ush*)(ws + V1H_OFF);   // also a3 hi
  ush*   v1l  = (ush*)(ws + V1L_OFF);   // also a3 lo
  float* t3   = ws + T3_OFF;            // also t4
  float* sA   = ws + STATS_OFF;
  float* sF   = sA + 512;
  float* sB   = sF + 128;
  int*   cellStart = (int*)(ws + CELLS_OFF);
  float4* sortedPos = (float4*)(ws + SPOS_OFF);

  // zero bf16 padded vols (halos!) + stats (ws poisoned 0xAA each call)
  k_zeroall<<<(ZN_ALL + 255) / 256, 256, 0, stream>>>(ws);
  k_prep_wt<<<1728, 256, 0, stream>>>(cw, wh, wl);
  k_bin<<<4, 256, 0, stream>>>(pos, cellStart, sortedPos);
  k_knn2<<<256, 64, 0, stream>>>(cellStart, sortedPos, idx);
  k_mlp<<<1024, 256, 0, stream>>>(pos, xf, pw1, pb1, pw2, pb2, fw, fb, uw, ubp, idx,
                                  vol0, v0h, v0l);
  // block 0 (16^3)
  k_convm<16><<<256, 256, 0, stream>>>(v0h, v0l, wh, wl, t1, sA);
  k_bnrelu<16><<<4096, 256, 0, stream>>>(t1, sA, v0h, v0l, 1.0f / 16384.0f); // a1
  k_convm<16><<<256, 256, 0, stream>>>(v0h, v0l, wh + WT_PER_CONV, wl + WT_PER_CONV,
                                       t1, sA + 128);                        // t2
  k_residpool<<<512, 256, 0, stream>>>(vol0, t1, sA + 128, vol1, v1h, v1l);
  // block 1 (8^3)
  k_convm<8><<<32, 256, 0, stream>>>(v1h, v1l, wh + 2 * WT_PER_CONV,
                                     wl + 2 * WT_PER_CONV, t3, sA + 256);
  k_bnrelu<8><<<512, 256, 0, stream>>>(t3, sA + 256, v1h, v1l, 1.0f / 2048.0f); // a3
  k_convm<8><<<32, 256, 0, stream>>>(v1h, v1l, wh + 3 * WT_PER_CONV,
                                     wl + 3 * WT_PER_CONV, t3, sA + 384);       // t4
  k_resid2<<<512, 256, 0, stream>>>(vol1, t3, sA + 384, sF, sB);
  // head
  k_final<<<1, 64, 0, stream>>>(sF, sB, ong, onb, row, rob, (float*)d_out);
}

// Round 5
// 349.297 us; speedup vs baseline: 2.9833x; 1.0662x over previous
//
#include <hip/hip_runtime.h>

#define ULL unsigned long long
typedef unsigned short ush;
typedef __attribute__((ext_vector_type(8))) short s8v;   // 8 bf16 (4 VGPRs)
typedef __attribute__((ext_vector_type(4))) float f4v;   // MFMA accumulator

// problem constants
#define BB 4
#define NP 4096
#define HH 64
#define EPSF 1e-5f

// workspace float offsets (ws is float*)
#define WH_OFF      0u           // [4][27][64][64] bf16 hi = 442368 bf16 = 221184 f
#define WL_OFF      221184u      // lo part
#define WT_PER_CONV 110592u      // bf16 elements per conv
#define IDX_OFF     442368u      // B*G*8 ints = 131072
#define VOL0_OFF    573440u      // fp32 padded [4][18][18][18][64] = 1492992 f
#define V0H_OFF     2066432u     // bf16 padded hi = 746496 f   } reused as a1 hi
#define V0L_OFF     2812928u     // bf16 padded lo = 746496 f   } reused as a1 lo
#define T1_OFF      3559424u     // fp32 [4][16][16][16][64] = 1048576 f (reused as t2)
#define VOL1_OFF    4608000u     // fp32 padded [4][10][10][10][64] = 256000 f
#define V1H_OFF     4864000u     // 128000 f  } reused as a3 hi
#define V1L_OFF     4992000u     // 128000 f  } reused as a3 lo
#define T3_OFF      5120000u     // fp32 [4][8][8][8][64] = 131072 f (reused as t4)
#define STATS_OFF   5251072u     // sA[4][128], sF[128], sB[4][64] = 896 f
#define CELLS_OFF   5251968u     // cellStart: 4 x 4097 ints (padded to 16400)
#define SPOS_OFF    5268368u     // sortedPos: 4 x 4096 float4 = 65536 f (16B aligned)
#define MW_OFF      5333904u     // mlp weights bf16: w2H,w2L,uwH,uwL 4x4096 ush = 8192 f

// merged zero ranges (float4 counts)
#define ZN_V0   373248u          // [V0H, T1)
#define ZN_V1   64000u           // [V1H, T3)
#define ZN_ST   224u             // stats
#define ZN_ALL  (ZN_V0 + ZN_V1 + ZN_ST)

__device__ __forceinline__ ush f2bf(float f) {            // fp32 -> bf16 RNE
  unsigned u = __float_as_uint(f);
  return (ush)((u + 0x7FFFu + ((u >> 16) & 1u)) >> 16);
}
__device__ __forceinline__ float bf2f(ush h) { return __uint_as_float(((unsigned)h) << 16); }

__device__ __forceinline__ float gelu_tanh(float v) {
  float inner = 0.7978845608028654f * (v + 0.044715f * v * v * v);
  return 0.5f * v * (1.0f + tanhf(inner));
}

__device__ __forceinline__ float lin16(int i) {
  return -1.0f + (float)i * (2.0f / 15.0f);
}

// --------------------------- fused: zero scratch + split conv/mlp weights to bf16
// conv_w [2][2][co][ci][3][3][3] -> wh/wl [conv][off=27][co][ci]
// pe_w2 / up_w [in][out]         -> mw: transposed [out][in] hi/lo x 2 matrices
__global__ __launch_bounds__(256) void k_prep(const float* __restrict__ cw,
                                              const float* __restrict__ pw2,
                                              const float* __restrict__ upw,
                                              ush* __restrict__ wh,
                                              ush* __restrict__ wl,
                                              ush* __restrict__ mw,
                                              float* __restrict__ ws) {
  unsigned i = blockIdx.x * 256u + threadIdx.x;
  float4 z = make_float4(0.f, 0.f, 0.f, 0.f);
  if (i < ZN_V0) ((float4*)(ws + V0H_OFF))[i] = z;
  else if (i < ZN_V0 + ZN_V1) ((float4*)(ws + V1H_OFF))[i - ZN_V0] = z;
  else if (i < ZN_ALL) ((float4*)(ws + STATS_OFF))[i - ZN_V0 - ZN_V1] = z;
  if (i < 442368u) {
    unsigned conv = i / WT_PER_CONV;
    unsigned r = i - conv * WT_PER_CONV;
    unsigned off = r >> 12;
    unsigned q = r & 4095u;
    unsigned co = q >> 6, ci = q & 63u;
    float w = cw[(conv * 4096u + co * 64u + ci) * 27u + off];
    ush hi = f2bf(w);
    wh[i] = hi;
    wl[i] = f2bf(w - bf2f(hi));
  } else if (i < 450560u) {
    unsigned t = i - 442368u;
    unsigned mat = t >> 12, r = t & 4095u;
    unsigned co = r >> 6, ci = r & 63u;       // out, in
    const float* src = mat ? upw : pw2;
    float w = src[ci * 64u + co];
    ush hi = f2bf(w);
    mw[mat * 8192u + co * 64u + ci] = hi;
    mw[mat * 8192u + 4096u + co * 64u + ci] = f2bf(w - bf2f(hi));
  }
}

// ------------------------------------------------- bin points to nearest voxel cell
__global__ __launch_bounds__(256) void k_bin(const float* __restrict__ pos,
                                             int* __restrict__ cellStart,
                                             float4* __restrict__ sortedPos) {
  __shared__ int cnt[4096];
  __shared__ int wsum[4];
  int tid = threadIdx.x;
  int b = blockIdx.x;
  const float* pb = pos + b * NP * 3;
  for (int i = tid; i < 4096; i += 256) cnt[i] = 0;
  __syncthreads();
#pragma unroll
  for (int t = 0; t < 16; ++t) {
    int p = t * 256 + tid;
    float px = pb[3 * p], py = pb[3 * p + 1], pz = pb[3 * p + 2];
    int c0 = (int)floorf((px + 1.0f) * 7.5f + 0.5f);
    int c1 = (int)floorf((py + 1.0f) * 7.5f + 0.5f);
    int c2 = (int)floorf((pz + 1.0f) * 7.5f + 0.5f);
    c0 = min(max(c0, 0), 15); c1 = min(max(c1, 0), 15); c2 = min(max(c2, 0), 15);
    atomicAdd(&cnt[(c0 * 16 + c1) * 16 + c2], 1);
  }
  __syncthreads();
  int base = tid * 16;
  int loc[16];
  int run = 0;
#pragma unroll
  for (int j = 0; j < 16; ++j) { loc[j] = run; run += cnt[base + j]; }
  int lane = tid & 63, wv = tid >> 6;
  int inc = run;
  for (int d = 1; d < 64; d <<= 1) {
    int o = __shfl_up(inc, d, 64);
    if (lane >= d) inc += o;
  }
  if (lane == 63) wsum[wv] = inc;
  __syncthreads();
  int woff = 0;
  for (int w = 0; w < wv; ++w) woff += wsum[w];
  int excl = woff + inc - run;
  __syncthreads();
  int stv[16];
#pragma unroll
  for (int j = 0; j < 16; ++j) {
    stv[j] = excl + loc[j];
    cellStart[b * 4097 + base + j] = stv[j];
  }
#pragma unroll
  for (int j = 0; j < 16; ++j) cnt[base + j] = stv[j];
  if (tid == 0) cellStart[b * 4097 + 4096] = NP;
  __syncthreads();
#pragma unroll
  for (int t = 0; t < 16; ++t) {
    int p = t * 256 + tid;
    float px = pb[3 * p], py = pb[3 * p + 1], pz = pb[3 * p + 2];
    int c0 = (int)floorf((px + 1.0f) * 7.5f + 0.5f);
    int c1 = (int)floorf((py + 1.0f) * 7.5f + 0.5f);
    int c2 = (int)floorf((pz + 1.0f) * 7.5f + 0.5f);
    c0 = min(max(c0, 0), 15); c1 = min(max(c1, 0), 15); c2 = min(max(c2, 0), 15);
    int slot = atomicAdd(&cnt[(c0 * 16 + c1) * 16 + c2], 1);
    sortedPos[b * 4096 + slot] = make_float4(px, py, pz, __int_as_float(p));
  }
}

// ------------------------------------------------- binned exact KNN (top-8)
__global__ __launch_bounds__(64) void k_knn2(const int* __restrict__ cellStart,
                                             const float4* __restrict__ sortedPos,
                                             int* __restrict__ idxo) {
  __shared__ int cs[4097];
  int tid = threadIdx.x;
  int vox = blockIdx.x * 64 + tid;
  int b = vox >> 12;
  int g = vox & 4095;
  for (int i = tid; i < 4097; i += 64) cs[i] = cellStart[b * 4097 + i];
  __syncthreads();
  int ii = g >> 8, jj = (g >> 4) & 15, kkc = g & 15;
  float gx = lin16(ii), gy = lin16(jj), gz = lin16(kkc);
  float gn = gx * gx + gy * gy + gz * gz;
  const float4* sp = sortedPos + b * 4096;
  ULL kk[8];
#pragma unroll
  for (int q = 0; q < 8; ++q) kk[q] = ~0ULL;
  for (int s = 0; s < 16; ++s) {
    int alo = max(ii - s, 0), ahi = min(ii + s, 15);
    int blo = max(jj - s, 0), bhi = min(jj + s, 15);
    int clo = max(kkc - s, 0), chi = min(kkc + s, 15);
    for (int a = alo; a <= ahi; ++a)
      for (int b2 = blo; b2 <= bhi; ++b2) {
        bool edge = (a == ii - s) || (a == ii + s) || (b2 == jj - s) || (b2 == jj + s);
        int cbase = (a * 16 + b2) * 16;
        int r0lo, r0hi, r1lo, r1hi;
        if (edge) { r0lo = clo; r0hi = chi; r1lo = 1; r1hi = 0; }
        else {
          r0lo = kkc - s; r0hi = kkc - s;
          if (kkc - s < 0) { r0lo = 1; r0hi = 0; }
          r1lo = kkc + s; r1hi = kkc + s;
          if (kkc + s > 15) { r1lo = 1; r1hi = 0; }
        }
#pragma unroll
        for (int rr = 0; rr < 2; ++rr) {
          int rlo = rr ? r1lo : r0lo, rhi = rr ? r1hi : r0hi;
          if (rlo > rhi) continue;
          int st = cs[cbase + rlo], en = cs[cbase + rhi + 1];
          for (int t = st; t < en; ++t) {
            float4 c = sp[t];
            float px = c.x, py = c.y, pz = c.z;
            float pn = px * px + py * py + pz * pz;
            float dt = gx * px + gy * py + gz * pz;
            float d = (gn + pn) - 2.0f * dt;
            unsigned u = __float_as_uint(d);
            u ^= (unsigned)((int)u >> 31) | 0x80000000u;
            ULL key = ((ULL)u << 32) | (unsigned)__float_as_uint(c.w);
            if (key < kk[7]) {
              kk[7] = key;
#pragma unroll
              for (int q2 = 7; q2 >= 1; --q2) {
                ULL x0 = kk[q2 - 1], x1 = kk[q2];
                bool sw = x1 < x0;
                kk[q2 - 1] = sw ? x1 : x0;
                kk[q2] = sw ? x0 : x1;
              }
            }
          }
        }
      }
    float bnd = ((float)s + 0.5f) * (2.0f / 15.0f) - 1e-5f;
    float b2f = bnd * bnd;
    unsigned ub = __float_as_uint(b2f) | 0x80000000u;
    if (((ULL)ub << 32) > kk[7]) break;
  }
#pragma unroll
  for (int q = 0; q < 8; ++q)
    idxo[(((b << 12) | g) << 3) + q] = (int)(kk[q] & 0xFFFFFFFFULL);
}

// ------------------------- fused bipartite conv + update MLP via MFMA (bf16x3)
// Block = 16 voxels = 128 (voxel,k) pairs, 4 waves.
// Phase0 (lane=channel): h1 = gelu(rel@W1+b1) -> LDS bf16 hi/lo; fe -> LDS fp32.
// GEMM1: PE = H1 @ W2 (wave owns 32 pairs = 2 M-tiles, all 4 N-tiles).
// Epilogue1: (PE+b2)*FE, 8-pair mean (r-sum + shfl_xor 16) -> agg LDS hi/lo.
// GEMM2: h = gelu(AGG @ UW + ub) -> vol0 fp32 + bf16 hi/lo (padded).
__global__ __launch_bounds__(256) void k_mlp2(
    const float* __restrict__ pos, const float* __restrict__ xf,
    const float* __restrict__ w1, const float* __restrict__ b1,
    const float* __restrict__ b2v, const float* __restrict__ fw,
    const float* __restrict__ fb, const float* __restrict__ ub,
    const ush* __restrict__ w2tH, const ush* __restrict__ w2tL,
    const ush* __restrict__ uwtH, const ush* __restrict__ uwtL,
    const int* __restrict__ idx, float* __restrict__ vol0,
    ush* __restrict__ v0h, ush* __restrict__ v0l) {
  __shared__ __align__(16) ush lhH[128 * 72];
  __shared__ __align__(16) ush lhL[128 * 72];
  __shared__ __align__(16) float lfe[128 * 68];
  __shared__ __align__(16) ush agH[16 * 72];
  __shared__ __align__(16) ush agL[16 * 72];
  int tid = threadIdx.x, lane = tid & 63, wv = tid >> 6;
  int lm = lane & 15, quad = lane >> 4;
  int b = blockIdx.x >> 8;
  int g0 = (blockIdx.x & 255) << 4;              // 16 consecutive g (z=0..15)
  // preload B-frags (weights stay in VGPRs the whole kernel)
  s8v BH[8], BL[8], UH[2], UL[2];
#pragma unroll
  for (int n = 0; n < 4; ++n)
#pragma unroll
    for (int ks = 0; ks < 2; ++ks) {
      int o = ((n * 16 + lm) << 6) + ks * 32 + (quad << 3);
      BH[n * 2 + ks] = *(const s8v*)(w2tH + o);
      BL[n * 2 + ks] = *(const s8v*)(w2tL + o);
    }
#pragma unroll
  for (int ks = 0; ks < 2; ++ks) {
    int o = ((wv * 16 + lm) << 6) + ks * 32 + (quad << 3);
    UH[ks] = *(const s8v*)(uwtH + o);
    UL[ks] = *(const s8v*)(uwtL + o);
  }
  float w10 = w1[lane], w11 = w1[64 + lane], w12 = w1[128 + lane], b1c = b1[lane];
  float fw0 = fw[lane], fw1 = fw[64 + lane], fw2 = fw[128 + lane], fbc = fb[lane];
  float gx = lin16(g0 >> 8), gy = lin16((g0 >> 4) & 15);
  // ---- phase 0: wave owns pairs [wv*32, wv*32+32) ----
  for (int i = 0; i < 32; ++i) {
    int pair = wv * 32 + i;
    int vi = pair >> 3, kk = pair & 7;
    int g = g0 + vi;
    float gz = lin16(vi);
    int p = idx[(((b << 12) | g) << 3) + kk];
    const float* pp = pos + (b * NP + p) * 3;
    float r0 = pp[0] - gx, r1 = pp[1] - gy, r2 = pp[2] - gz;
    float h1 = gelu_tanh(fmaf(r2, w12, fmaf(r1, w11, fmaf(r0, w10, b1c))));
    const float* xp = xf + (b * NP + p) * 3;
    float fe = fmaf(xp[2], fw2, fmaf(xp[1], fw1, fmaf(xp[0], fw0, fbc)));
    ush hi = f2bf(h1);
    lhH[pair * 72 + lane] = hi;
    lhL[pair * 72 + lane] = f2bf(h1 - bf2f(hi));
    lfe[pair * 68 + lane] = fe;
  }
  // ---- GEMM1 (reads only this wave's LDS rows; DS ops in-order per wave) ----
  f4v acc[2][4];
#pragma unroll
  for (int m = 0; m < 2; ++m)
#pragma unroll
    for (int n = 0; n < 4; ++n) acc[m][n] = (f4v){0.f, 0.f, 0.f, 0.f};
#pragma unroll
  for (int m = 0; m < 2; ++m)
#pragma unroll
    for (int ks = 0; ks < 2; ++ks) {
      int ao = (wv * 32 + m * 16 + lm) * 72 + ks * 32 + quad * 8;
      s8v Ah = *(const s8v*)&lhH[ao];
      s8v Al = *(const s8v*)&lhL[ao];
#pragma unroll
      for (int n = 0; n < 4; ++n) {
        acc[m][n] = __builtin_amdgcn_mfma_f32_16x16x32_bf16(Ah, BH[n * 2 + ks], acc[m][n], 0, 0, 0);
        acc[m][n] = __builtin_amdgcn_mfma_f32_16x16x32_bf16(Ah, BL[n * 2 + ks], acc[m][n], 0, 0, 0);
        acc[m][n] = __builtin_amdgcn_mfma_f32_16x16x32_bf16(Al, BH[n * 2 + ks], acc[m][n], 0, 0, 0);
      }
    }
  // ---- epilogue1: msg = (pe+b2)*fe, mean over 8 pairs -> agg LDS ----
  float b2c[4];
#pragma unroll
  for (int n = 0; n < 4; ++n) b2c[n] = b2v[n * 16 + lm];
#pragma unroll
  for (int m = 0; m < 2; ++m) {
    int vox = wv * 4 + m * 2 + (quad >> 1);
#pragma unroll
    for (int n = 0; n < 4; ++n) {
      float s = 0.0f;
#pragma unroll
      for (int r = 0; r < 4; ++r) {
        int pair = wv * 32 + m * 16 + quad * 4 + r;
        s += (acc[m][n][r] + b2c[n]) * lfe[pair * 68 + n * 16 + lm];
      }
      s += __shfl_xor(s, 16, 64);                // quad0+1 / quad2+3
      s *= 0.125f;
      if ((quad & 1) == 0) {
        ush hi = f2bf(s);
        agH[vox * 72 + n * 16 + lm] = hi;
        agL[vox * 72 + n * 16 + lm] = f2bf(s - bf2f(hi));
      }
    }
  }
  __syncthreads();
  // ---- GEMM2: wave = N-tile wv over all 16 voxels ----
  f4v a2 = (f4v){0.f, 0.f, 0.f, 0.f};
#pragma unroll
  for (int ks = 0; ks < 2; ++ks) {
    int ao = lm * 72 + ks * 32 + quad * 8;
    s8v Ah = *(const s8v*)&agH[ao];
    s8v Al = *(const s8v*)&agL[ao];
    a2 = __builtin_amdgcn_mfma_f32_16x16x32_bf16(Ah, UH[ks], a2, 0, 0, 0);
    a2 = __builtin_amdgcn_mfma_f32_16x16x32_bf16(Ah, UL[ks], a2, 0, 0, 0);
    a2 = __builtin_amdgcn_mfma_f32_16x16x32_bf16(Al, UH[ks], a2, 0, 0, 0);
  }
  float ubc = ub[wv * 16 + lm];
  int xc = g0 >> 8, yc = (g0 >> 4) & 15;
#pragma unroll
  for (int r = 0; r < 4; ++r) {
    int vox = quad * 4 + r;                      // == z coordinate
    float h = gelu_tanh(a2[r] + ubc);
    int pidx = (((b * 18 + vox + 1) * 18 + yc + 1) * 18 + xc + 1) * 64 + wv * 16 + lm;
    vol0[pidx] = h;
    ush hi = f2bf(h);
    v0h[pidx] = hi;
    v0l[pidx] = f2bf(h - bf2f(hi));
  }
}

// ------------------------------------------- MFMA implicit-GEMM 3x3x3 conv (bf16x3)
template <int Z>
__global__ __launch_bounds__(256) void k_convm(const ush* __restrict__ vh,
                                               const ush* __restrict__ vl,
                                               const ush* __restrict__ wh,
                                               const ush* __restrict__ wl,
                                               float* __restrict__ out,
                                               float* __restrict__ stats) {
  constexpr int P = Z + 2;
  constexpr int Py = (Z == 16) ? 6 : 10;
  constexpr int Px = (Z == 16) ? 18 : 10;
  constexpr int NV = 3 * Py * Px;
  constexpr int VS = 272;
  __shared__ unsigned char slab[NV * VS];
  __shared__ float ls[64], ls2[64];
  int tid = threadIdx.x;
  int lane = tid & 63, wv = tid >> 6;
  int vbase = blockIdx.x * 64;
  int b = (Z == 16) ? (vbase >> 12) : (vbase >> 9);
  int rem = vbase & (Z * Z * Z - 1);
  int z0 = rem / (Z * Z);
  int y0 = (Z == 16) ? ((rem & 255) >> 4) : 0;
  if (tid < 64) { ls[tid] = 0.0f; ls2[tid] = 0.0f; }
  {
    constexpr int NCH = NV * 8;
    for (int i = tid; i < NCH; i += 256) {
      int v = i >> 3, c = i & 7;
      int lz = v / (Py * Px);
      int r = v - lz * (Py * Px);
      int ly = r / Px, lx = r - ly * Px;
      int g = (((b * P + z0 + lz) * P + (y0 + ly)) * P + lx) * 64 + c * 8;
      *(uint4*)(slab + v * VS + c * 16)       = *(const uint4*)(vh + g);
      *(uint4*)(slab + v * VS + 128 + c * 16) = *(const uint4*)(vl + g);
    }
  }
  __syncthreads();
  int lm = lane & 15, quad = lane >> 4;
  int co = (wv << 4) | lm;
  f4v acc[4];
#pragma unroll
  for (int m = 0; m < 4; ++m) acc[m] = (f4v){0.f, 0.f, 0.f, 0.f};
  for (int off = 0; off < 27; ++off) {
    int dz = off / 9, r9 = off - dz * 9, dy = r9 / 3, dx = r9 - dy * 3;
    const ush* bph = wh + ((off * 64 + co) << 6) + (quad << 3);
    const ush* bpl = wl + ((off * 64 + co) << 6) + (quad << 3);
#pragma unroll
    for (int ks = 0; ks < 2; ++ks) {
      s8v bhf = *(const s8v*)(bph + ks * 32);
      s8v blf = *(const s8v*)(bpl + ks * 32);
#pragma unroll
      for (int m = 0; m < 4; ++m) {
        int lyp, lxp;
        if (Z == 16) { lyp = m + dy; lxp = lm + dx; }
        else         { lyp = 2 * m + (lm >> 3) + dy; lxp = (lm & 7) + dx; }
        int sv = (dz * Py + lyp) * Px + lxp;
        const unsigned char* ap = slab + sv * VS + (quad << 4) + (ks << 6);
        s8v ahf = *(const s8v*)(ap);
        s8v alf = *(const s8v*)(ap + 128);
        acc[m] = __builtin_amdgcn_mfma_f32_16x16x32_bf16(ahf, bhf, acc[m], 0, 0, 0);
        acc[m] = __builtin_amdgcn_mfma_f32_16x16x32_bf16(ahf, blf, acc[m], 0, 0, 0);
        acc[m] = __builtin_amdgcn_mfma_f32_16x16x32_bf16(alf, bhf, acc[m], 0, 0, 0);
      }
    }
  }
  float s = 0.0f, s2 = 0.0f;
#pragma unroll
  for (int m = 0; m < 4; ++m) {
    int vx = vbase + (m << 4) + (quad << 2);
#pragma unroll
    for (int r = 0; r < 4; ++r) {
      float v = acc[m][r];
      out[(vx + r) * 64 + co] = v;
      s += v;
      s2 = fmaf(v, v, s2);
    }
  }
  atomicAdd(&ls[co], s);
  atomicAdd(&ls2[co], s2);
  __syncthreads();
  if (tid < 64) {
    atomicAdd(&stats[tid * 2], ls[tid]);
    atomicAdd(&stats[tid * 2 + 1], ls2[tid]);
  }
}

// ------------------------------------ relu(bn(x)) -> padded bf16 hi/lo volumes
template <int Z>
__global__ __launch_bounds__(256) void k_bnrelu(const float* __restrict__ t,
                                                const float* __restrict__ stats,
                                                ush* __restrict__ outh,
                                                ush* __restrict__ outl,
                                                float inv_cnt) {
  constexpr int P = Z + 2;
  unsigned i = blockIdx.x * 256u + threadIdx.x;
  int c = i & 63;
  int vox = i >> 6;
  int x = vox % Z;
  int q = vox / Z;
  int y = q % Z;
  q /= Z;
  int z = q % Z;
  int b = q / Z;
  float m = stats[c * 2] * inv_cnt;
  float var = stats[c * 2 + 1] * inv_cnt - m * m;
  float rs = 1.0f / sqrtf(var + EPSF);
  float v = (t[i] - m) * rs;
  v = v > 0.0f ? v : 0.0f;
  int pidx = (((b * P + z + 1) * P + y + 1) * P + x + 1) * 64 + c;
  ush hi = f2bf(v);
  outh[pidx] = hi;
  outl[pidx] = f2bf(v - bf2f(hi));
}

// --------------------------------- vol = relu(vol0 + bn(t2)) then 2x2x2 maxpool
__global__ __launch_bounds__(256) void k_residpool(const float* __restrict__ vol0,
                                                   const float* __restrict__ t2,
                                                   const float* __restrict__ stats,
                                                   float* __restrict__ vol1,
                                                   ush* __restrict__ v1h,
                                                   ush* __restrict__ v1l) {
  unsigned i = blockIdx.x * 256u + threadIdx.x;
  int c = i & 63;
  int pv = i >> 6;
  int xp = pv & 7, yp = (pv >> 3) & 7, zp = (pv >> 6) & 7, b = pv >> 9;
  float m = stats[c * 2] * (1.0f / 16384.0f);
  float var = stats[c * 2 + 1] * (1.0f / 16384.0f) - m * m;
  float rs = 1.0f / sqrtf(var + EPSF);
  float best = 0.0f;
  for (int dz = 0; dz < 2; ++dz)
    for (int dy = 0; dy < 2; ++dy)
      for (int dx = 0; dx < 2; ++dx) {
        int z = 2 * zp + dz, y = 2 * yp + dy, x = 2 * xp + dx;
        float a = vol0[(((b * 18 + z + 1) * 18 + y + 1) * 18 + x + 1) * 64 + c];
        float t = t2[(b * 4096 + z * 256 + y * 16 + x) * 64 + c];
        float u = a + (t - m) * rs;
        u = u > 0.0f ? u : 0.0f;
        best = u > best ? u : best;
      }
  int pidx = (((b * 10 + zp + 1) * 10 + yp + 1) * 10 + xp + 1) * 64 + c;
  vol1[pidx] = best;
  ush hi = f2bf(best);
  v1h[pidx] = hi;
  v1l[pidx] = f2bf(best - bf2f(hi));
}

// -------------------- vol2 = relu(vol1 + bn(t4)); only its BN stats are needed
__global__ __launch_bounds__(256) void k_resid2(const float* __restrict__ vol1,
                                                const float* __restrict__ t4,
                                                const float* __restrict__ stats,
                                                float* __restrict__ sF,
                                                float* __restrict__ sB) {
  __shared__ float ls[64], ls2[64];
  if (threadIdx.x < 64) { ls[threadIdx.x] = 0.0f; ls2[threadIdx.x] = 0.0f; }
  __syncthreads();
  unsigned i = blockIdx.x * 256u + threadIdx.x;
  int c = i & 63;
  int pv = i >> 6;
  int x = pv & 7, y = (pv >> 3) & 7, z = (pv >> 6) & 7, b = pv >> 9;
  float m = stats[c * 2] * (1.0f / 2048.0f);
  float var = stats[c * 2 + 1] * (1.0f / 2048.0f) - m * m;
  float rs = 1.0f / sqrtf(var + EPSF);
  float a = vol1[(((b * 10 + z + 1) * 10 + y + 1) * 10 + x + 1) * 64 + c];
  float u = a + (t4[i] - m) * rs;
  u = u > 0.0f ? u : 0.0f;
  atomicAdd(&ls[c], u);
  atomicAdd(&ls2[c], u * u);
  __syncthreads();
  if (threadIdx.x < 64) {
    int cc = threadIdx.x;
    atomicAdd(&sF[cc * 2], ls[cc]);
    atomicAdd(&sF[cc * 2 + 1], ls2[cc]);
    atomicAdd(&sB[b * 64 + cc], ls[cc]);
  }
}

// ------------- final bn affine + spatial mean pool + linear head -> [4,16]
__global__ __launch_bounds__(64) void k_final(const float* __restrict__ sF,
                                              const float* __restrict__ sB,
                                              const float* __restrict__ ong,
                                              const float* __restrict__ onb,
                                              const float* __restrict__ row,
                                              const float* __restrict__ rob,
                                              float* __restrict__ outp) {
  __shared__ float pl[4][64];
  int c = threadIdx.x;
  float m = sF[c * 2] * (1.0f / 2048.0f);
  float var = sF[c * 2 + 1] * (1.0f / 2048.0f) - m * m;
  float rs = 1.0f / sqrtf(var + EPSF);
  float gg = ong[c], bb = onb[c];
  for (int b = 0; b < 4; ++b)
    pl[b][c] = (sB[b * 64 + c] * (1.0f / 512.0f) - m) * rs * gg + bb;
  __syncthreads();
  int b = threadIdx.x >> 4, o = threadIdx.x & 15;
  float s = rob[o];
  for (int j = 0; j < 64; ++j) s = fmaf(pl[b][j], row[j * 16 + o], s);
  outp[b * 16 + o] = s;
}

extern "C" void kernel_launch(void* const* d_in, const int* in_sizes, int n_in,
                              void* d_out, int out_size, void* d_ws, size_t ws_size,
                              hipStream_t stream) {
  (void)in_sizes; (void)n_in; (void)out_size; (void)ws_size;
  const float* pos = (const float*)d_in[0];
  const float* xf  = (const float*)d_in[1];
  const float* pw1 = (const float*)d_in[2];
  const float* pb1 = (const float*)d_in[3];
  const float* pw2 = (const float*)d_in[4];
  const float* pb2 = (const float*)d_in[5];
  const float* fw  = (const float*)d_in[6];
  const float* fb  = (const float*)d_in[7];
  const float* uw  = (const float*)d_in[8];
  const float* ubp = (const float*)d_in[9];
  const float* cw  = (const float*)d_in[10];
  // d_in[11] = conv_b: unused (training-mode BN cancels conv bias exactly)
  const float* ong = (const float*)d_in[12];
  const float* onb = (const float*)d_in[13];
  const float* row = (const float*)d_in[14];
  const float* rob = (const float*)d_in[15];

  float* ws   = (float*)d_ws;
  ush*   wh   = (ush*)(ws + WH_OFF);
  ush*   wl   = (ush*)(ws + WL_OFF);
  int*   idx  = (int*)(ws + IDX_OFF);
  float* vol0 = ws + VOL0_OFF;
  ush*   v0h  = (ush*)(ws + V0H_OFF);   // also a1 hi
  ush*   v0l  = (ush*)(ws + V0L_OFF);   // also a1 lo
  float* t1   = ws + T1_OFF;            // also t2
  float* vol1 = ws + VOL1_OFF;
  ush*   v1h  = (ush*)(ws + V1H_OFF);   // also a3 hi
  ush*   v1l  = (ush*)(ws + V1L_OFF);   // also a3 lo
  float* t3   = ws + T3_OFF;            // also t4
  float* sA   = ws + STATS_OFF;
  float* sF   = sA + 512;
  float* sB   = sF + 128;
  int*   cellStart = (int*)(ws + CELLS_OFF);
  float4* sortedPos = (float4*)(ws + SPOS_OFF);
  ush*   mw   = (ush*)(ws + MW_OFF);    // [w2H|w2L|uwH|uwL] each 4096 ush

  k_prep<<<1760, 256, 0, stream>>>(cw, pw2, uw, wh, wl, mw, ws);
  k_bin<<<4, 256, 0, stream>>>(pos, cellStart, sortedPos);
  k_knn2<<<256, 64, 0, stream>>>(cellStart, sortedPos, idx);
  k_mlp2<<<1024, 256, 0, stream>>>(pos, xf, pw1, pb1, pb2, fw, fb, ubp,
                                   mw, mw + 4096, mw + 8192, mw + 12288,
                                   idx, vol0, v0h, v0l);
  // block 0 (16^3)
  k_convm<16><<<256, 256, 0, stream>>>(v0h, v0l, wh, wl, t1, sA);
  k_bnrelu<16><<<4096, 256, 0, stream>>>(t1, sA, v0h, v0l, 1.0f / 16384.0f); // a1
  k_convm<16><<<256, 256, 0, stream>>>(v0h, v0l, wh + WT_PER_CONV, wl + WT_PER_CONV,
                                       t1, sA + 128);                        // t2
  k_residpool<<<512, 256, 0, stream>>>(vol0, t1, sA + 128, vol1, v1h, v1l);
  // block 1 (8^3)
  k_convm<8><<<32, 256, 0, stream>>>(v1h, v1l, wh + 2 * WT_PER_CONV,
                                     wl + 2 * WT_PER_CONV, t3, sA + 256);
  k_bnrelu<8><<<512, 256, 0, stream>>>(t3, sA + 256, v1h, v1l, 1.0f / 2048.0f); // a3
  k_convm<8><<<32, 256, 0, stream>>>(v1h, v1l, wh + 3 * WT_PER_CONV,
                                     wl + 3 * WT_PER_CONV, t3, sA + 384);       // t4
  k_resid2<<<512, 256, 0, stream>>>(vol1, t3, sA + 384, sF, sB);
  // head
  k_final<<<1, 64, 0, stream>>>(sF, sB, ong, onb, row, rob, (float*)d_out);
}